// Round 6
// baseline (1858.174 us; speedup 1.0000x reference)
//
#include <hip/hip_runtime.h>
#include <hip/hip_bf16.h>
#include <hip/hip_fp16.h>

// GCN inference: conv1(128->16)+ReLU -> conv2(16->16) -> linear(16->40) -> log_softmax
// R13 post-mortem: fp16 gather tables worked (445->404); bucketsort top again
// (80us, width-capped 391 blocks). R14: delete bucketsort+edata+offs entirely.
// Re-do R10's bucket-LDS-accumulator agg with plain atomicAdd on __shared__
// float (R10 used unsafeAtomicAdd -- the GLOBAL unsafe-fp hook -- on a shared
// pointer, which lowered to a CAS retry storm; native ds_add_f32 exists and
// LLVM emits it for plain atomicAdd on LDS). 782 buckets x 128 nodes: acc
// tile 8KB, grid 3/CU. Weighted degree folds into k_partition via global
// unsafeAtomicAdd (intended use). fp16 h1/hb retained (L2-resident gathers).
// Falsifier: aggm >= 300us => CAS theory wrong, revert to sort next round.

#define N_NODES 100000
#define N_EDGES 6400000
#define IN_DIM  128
#define HID     16
#define NCLS    40

#define K_BKT    782         // buckets = col>>7, 128 nodes each (last: 32)
#define BKT_SH   7
#define BKT_NB   128         // nodes per bucket
#define BKT_MASK 127
#define B_PART   1000        // histogram/partition blocks
#define CHUNK    6400        // edges per partition block (fits LDS staging)

// ---- tier-1 workspace layout (bytes) ----
#define OFF_CB     0          // int[783] bucket bases
#define OFF_TOT    4096       // int[782] bucket totals
#define OFF_DINV   8192       // float[N]: deg accum (init 1.0), rsqrt in place
#define OFF_EBUF1  408192     // int2[E] bucket-major edges (LIVE through aggm2)
#define OFF_HISTC  51608192   // int[1000*782]
#define OFF_HISTEX 54736192   // int[1000*782]
#define OFF_H1     57864192   // __half[N*16]
#define OFF_HB     61064192   // __half[N*16]  (ends 64.3MB)
#define WS_T1_NEED 103600000  // unchanged threshold

// ---- tier-2 workspace layout (R5 atomic-CSR path, fp16 h) ----
#define T2_DINV  0
#define T2_CNT   400128
#define T2_OFFS  800256
#define T2_EDATA 1200384
#define T2_H1    52400384
#define T2_HB    58800384
#define T2_BSUM  65200384
#define WS_T2_NEED 65210000

// ---- tier-3 fallback layout ----
#define OFF3_DEG 0
#define OFF3_H1  400128
#define OFF3_HB  6800384

// =================== tier-1: bucket-major build ===================

__global__ __launch_bounds__(1024) void k_hist(const int* col, int* histcnt) {
    __shared__ int h[K_BKT];
    int t = threadIdx.x;
    if (t < K_BKT) h[t] = 0;
    __syncthreads();
    int b = blockIdx.x;
    int end = (b + 1) * CHUNK;
    int e = b * CHUNK + t;
    for (; e + 3072 < end; e += 4096) {
        int c0 = col[e];
        int c1 = col[e + 1024];
        int c2 = col[e + 2048];
        int c3 = col[e + 3072];
        atomicAdd(&h[c0 >> BKT_SH], 1);               // LDS int atomic: fast path
        atomicAdd(&h[c1 >> BKT_SH], 1);
        atomicAdd(&h[c2 >> BKT_SH], 1);
        atomicAdd(&h[c3 >> BKT_SH], 1);
    }
    for (; e < end; e += 1024)
        atomicAdd(&h[col[e] >> BKT_SH], 1);
    __syncthreads();
    if (t < K_BKT) histcnt[b * K_BKT + t] = h[t];
}

// one block per bucket k: exclusive-scan histcnt[.][k] over the 1000 blocks
__global__ __launch_bounds__(1024) void k_colscan(const int* histcnt, int* histex, int* tot) {
    __shared__ int s[1024];
    int t = threadIdx.x;
    int k = blockIdx.x;
    int v = (t < B_PART) ? histcnt[t * K_BKT + k] : 0;
    s[t] = v;
    __syncthreads();
    for (int o = 1; o < 1024; o <<= 1) {
        int a = (t >= o) ? s[t - o] : 0;
        __syncthreads();
        s[t] += a;
        __syncthreads();
    }
    if (t < B_PART) histex[t * K_BKT + k] = s[t] - v;  // exclusive
    if (t == 0) tot[k] = s[B_PART - 1];                // inclusive total
}

__global__ __launch_bounds__(1024) void k_basescan(const int* tot, int* cbase) {
    __shared__ int s[1024];
    int t = threadIdx.x;
    int v = (t < K_BKT) ? tot[t] : 0;
    s[t] = v;
    __syncthreads();
    for (int o = 1; o < 1024; o <<= 1) {
        int a = (t >= o) ? s[t - o] : 0;
        __syncthreads();
        s[t] += a;
        __syncthreads();
    }
    if (t < K_BKT) cbase[t] = s[t] - v;               // exclusive
    if (t == 0) cbase[K_BKT] = N_EDGES;
}

// LDS-staged partition + weighted-degree accumulation (global f32 atomics,
// fire-and-forget). packed = row | (col_local<<17)
__global__ __launch_bounds__(1024) void k_partition(const int* row, const int* col,
                                                    const float* w, const int* histcnt,
                                                    const int* histex, const int* cbase,
                                                    int2* ebuf1, float* deg) {
    __shared__ int2 led[CHUNK];          // 51.2KB staged edges (local sorted order)
    __shared__ int  sscan[1024];
    __shared__ int  lbase[K_BKT + 1];    // local exclusive offsets
    __shared__ int  gofs[K_BKT];         // global_base - local_base per bucket
    __shared__ int  cur[K_BKT];
    int t = threadIdx.x;
    int b = blockIdx.x;
    // local exclusive scan of this block's bucket counts
    int v = (t < K_BKT) ? histcnt[b * K_BKT + t] : 0;
    sscan[t] = v;
    __syncthreads();
    for (int o = 1; o < 1024; o <<= 1) {
        int a = (t >= o) ? sscan[t - o] : 0;
        __syncthreads();
        sscan[t] += a;
        __syncthreads();
    }
    if (t < K_BKT) {
        int ex = sscan[t] - v;
        lbase[t] = ex;
        cur[t] = ex;
        gofs[t] = cbase[t] + histex[b * K_BKT + t] - ex;
    }
    if (t == 0) lbase[K_BKT] = CHUNK;
    __syncthreads();
    // local scatter into LDS (2x unrolled) + deg atomics
    int end = (b + 1) * CHUNK;
    int e = b * CHUNK + t;
    for (; e + 1024 < end; e += 2048) {
        int c0 = col[e],  c1 = col[e + 1024];
        int r0 = row[e],  r1 = row[e + 1024];
        float w0 = w[e],  w1 = w[e + 1024];
        int p0 = atomicAdd(&cur[c0 >> BKT_SH], 1);
        int p1 = atomicAdd(&cur[c1 >> BKT_SH], 1);
        unsafeAtomicAdd(&deg[c0], w0);                // global f32 fire-and-forget
        unsafeAtomicAdd(&deg[c1], w1);
        led[p0] = make_int2(r0 | ((c0 & BKT_MASK) << 17), __float_as_int(w0));
        led[p1] = make_int2(r1 | ((c1 & BKT_MASK) << 17), __float_as_int(w1));
    }
    for (; e < end; e += 1024) {
        int c = col[e];
        float wv = w[e];
        int p = atomicAdd(&cur[c >> BKT_SH], 1);
        unsafeAtomicAdd(&deg[c], wv);
        led[p] = make_int2(row[e] | ((c & BKT_MASK) << 17), __float_as_int(wv));
    }
    __syncthreads();
    // write-out in slot order -> coalesced runs per bucket segment
    for (int i = t; i < CHUNK; i += 1024) {
        int2 ed = led[i];
        int lo = 0, hi = K_BKT;          // find k: lbase[k] <= i < lbase[k+1]
        while (hi - lo > 1) {
            int mid = (lo + hi) >> 1;
            if (lbase[mid] <= i) lo = mid; else hi = mid;
        }
        ebuf1[gofs[lo] + i] = ed;
    }
}

// =================== shared compute kernels ===================

// h1 = fp16(dinv[node] * (z @ W1)) -- fp16 so gather table (3.2MB) is L2-resident
__global__ __launch_bounds__(256) void k_gemm1(const float* z, const float* W1,
                                               __half* h1, const float* dinv) {
    __shared__ float w1s[IN_DIM * HID];
    __shared__ float zs[64 * 132];
    int tid = threadIdx.x;
    for (int i = tid; i < IN_DIM * HID / 4; i += 256)
        ((float4*)w1s)[i] = ((const float4*)W1)[i];
    int nodeBase = blockIdx.x * 64;
    for (int i = tid; i < 64 * 32; i += 256) {
        int nl = i >> 5, kq = i & 31;
        int node = nodeBase + nl;
        float4 v = (node < N_NODES) ? ((const float4*)z)[node * 32 + kq]
                                    : make_float4(0.f, 0.f, 0.f, 0.f);
        *(float4*)&zs[nl * 132 + kq * 4] = v;
    }
    __syncthreads();
    int nl = tid >> 2;
    int jb = (tid & 3) * 4;
    int node = nodeBase + nl;
    float4 acc = make_float4(0.f, 0.f, 0.f, 0.f);
    for (int k = 0; k < IN_DIM; k++) {
        float s = zs[nl * 132 + k];
        float4 wv = *(const float4*)&w1s[k * HID + jb];
        acc.x += s * wv.x; acc.y += s * wv.y; acc.z += s * wv.z; acc.w += s * wv.w;
    }
    if (node < N_NODES) {
        float dv = dinv ? dinv[node] : 1.0f;
        union { __half2 h2[2]; uint2 u; } pk;
        pk.h2[0] = __floats2half2_rn(acc.x * dv, acc.y * dv);
        pk.h2[1] = __floats2half2_rn(acc.z * dv, acc.w * dv);
        ((uint2*)h1)[node * 4 + (tid & 3)] = pk.u;    // 8B store: 4 halves
    }
}

// f32-output variant for tier-3
__global__ __launch_bounds__(256) void k_gemm1f(const float* z, const float* W1, float* h1,
                                                const float* dinv) {
    __shared__ float w1s[IN_DIM * HID];
    __shared__ float zs[64 * 132];
    int tid = threadIdx.x;
    for (int i = tid; i < IN_DIM * HID / 4; i += 256)
        ((float4*)w1s)[i] = ((const float4*)W1)[i];
    int nodeBase = blockIdx.x * 64;
    for (int i = tid; i < 64 * 32; i += 256) {
        int nl = i >> 5, kq = i & 31;
        int node = nodeBase + nl;
        float4 v = (node < N_NODES) ? ((const float4*)z)[node * 32 + kq]
                                    : make_float4(0.f, 0.f, 0.f, 0.f);
        *(float4*)&zs[nl * 132 + kq * 4] = v;
    }
    __syncthreads();
    int nl = tid >> 2;
    int jb = (tid & 3) * 4;
    int node = nodeBase + nl;
    float4 acc = make_float4(0.f, 0.f, 0.f, 0.f);
    for (int k = 0; k < IN_DIM; k++) {
        float s = zs[nl * 132 + k];
        float4 wv = *(const float4*)&w1s[k * HID + jb];
        acc.x += s * wv.x; acc.y += s * wv.y; acc.z += s * wv.z; acc.w += s * wv.w;
    }
    if (node < N_NODES) {
        float dv = dinv ? dinv[node] : 1.0f;
        acc.x *= dv; acc.y *= dv; acc.z *= dv; acc.w *= dv;
        ((float4*)h1)[node * 4 + (tid & 3)] = acc;
    }
}

// ---- tier-1 bucket aggregation: LDS f32 accumulators (ds_add_f32 path) ----

// conv1 aggregate (+b1, ReLU), fused h2 = x1 @ W2; hb = fp16(dinv * h2)
__global__ __launch_bounds__(1024) void k_aggm1(const int2* __restrict__ ebuf1,
                                                const int* __restrict__ cbase,
                                                const __half* __restrict__ h1,
                                                const float* __restrict__ dinv,
                                                const float* __restrict__ b1,
                                                const float* __restrict__ W2,
                                                __half* __restrict__ hb) {
    __shared__ float acc[BKT_NB * HID];               // 8KB
    __shared__ float w2s[HID * HID];
    int tid = threadIdx.x;
    int k = blockIdx.x;
    if (tid < HID * HID) w2s[tid] = W2[tid];
    for (int i = tid; i < BKT_NB * HID; i += 1024) acc[i] = 0.0f;
    __syncthreads();
    int e0 = cbase[k], e1 = cbase[k + 1];
    int lane = tid & 15;
    int e = e0 + (tid >> 4);                          // 64 groups of 16 lanes
    for (; e + 192 < e1; e += 256) {
        int2 v0 = ebuf1[e];
        int2 v1 = ebuf1[e + 64];
        int2 v2 = ebuf1[e + 128];
        int2 v3 = ebuf1[e + 192];
        float g0 = __half2float(h1[(v0.x & 131071) * HID + lane]);
        float g1 = __half2float(h1[(v1.x & 131071) * HID + lane]);
        float g2 = __half2float(h1[(v2.x & 131071) * HID + lane]);
        float g3 = __half2float(h1[(v3.x & 131071) * HID + lane]);
        atomicAdd(&acc[(v0.x >> 17) * HID + lane], __int_as_float(v0.y) * g0);
        atomicAdd(&acc[(v1.x >> 17) * HID + lane], __int_as_float(v1.y) * g1);
        atomicAdd(&acc[(v2.x >> 17) * HID + lane], __int_as_float(v2.y) * g2);
        atomicAdd(&acc[(v3.x >> 17) * HID + lane], __int_as_float(v3.y) * g3);
    }
    for (; e < e1; e += 64) {
        int2 v = ebuf1[e];
        atomicAdd(&acc[(v.x >> 17) * HID + lane],
                  __int_as_float(v.y) * __half2float(h1[(v.x & 131071) * HID + lane]));
    }
    __syncthreads();
    // finish 1: x1 = relu(dinv*(acc + self) + b1), back into acc
    for (int i = tid; i < BKT_NB * HID; i += 1024) {
        int node = k * BKT_NB + (i >> 4);
        if (node < N_NODES) {
            float v = dinv[node] * (acc[i] + __half2float(h1[node * HID + (i & 15)]))
                      + b1[i & 15];
            acc[i] = fmaxf(v, 0.0f);
        }
    }
    __syncthreads();
    // finish 2: hb = fp16(dinv * (x1 @ W2))
    for (int i = tid; i < BKT_NB * HID; i += 1024) {
        int nl = i >> 4, f = i & 15;
        int node = k * BKT_NB + nl;
        if (node < N_NODES) {
            float h2 = 0.0f;
            #pragma unroll
            for (int kk = 0; kk < HID; kk++) h2 += acc[nl * HID + kk] * w2s[kk * HID + f];
            hb[node * HID + f] = __float2half(dinv[node] * h2);
        }
    }
}

// conv2 aggregate (+b2), classifier (16->40) + log_softmax
__global__ __launch_bounds__(1024) void k_aggm2(const int2* __restrict__ ebuf1,
                                                const int* __restrict__ cbase,
                                                const __half* __restrict__ hb,
                                                const float* __restrict__ dinv,
                                                const float* __restrict__ b2,
                                                const float* __restrict__ Wc,
                                                const float* __restrict__ bc,
                                                float* __restrict__ out) {
    __shared__ float acc[BKT_NB * HID];
    __shared__ float wcs[HID * NCLS];
    __shared__ float bcs[NCLS];
    int tid = threadIdx.x;
    int k = blockIdx.x;
    for (int i = tid; i < HID * NCLS; i += 1024) wcs[i] = Wc[i];
    if (tid < NCLS) bcs[tid] = bc[tid];
    for (int i = tid; i < BKT_NB * HID; i += 1024) acc[i] = 0.0f;
    __syncthreads();
    int e0 = cbase[k], e1 = cbase[k + 1];
    int lane = tid & 15;
    int e = e0 + (tid >> 4);
    for (; e + 192 < e1; e += 256) {
        int2 v0 = ebuf1[e];
        int2 v1 = ebuf1[e + 64];
        int2 v2 = ebuf1[e + 128];
        int2 v3 = ebuf1[e + 192];
        float g0 = __half2float(hb[(v0.x & 131071) * HID + lane]);
        float g1 = __half2float(hb[(v1.x & 131071) * HID + lane]);
        float g2 = __half2float(hb[(v2.x & 131071) * HID + lane]);
        float g3 = __half2float(hb[(v3.x & 131071) * HID + lane]);
        atomicAdd(&acc[(v0.x >> 17) * HID + lane], __int_as_float(v0.y) * g0);
        atomicAdd(&acc[(v1.x >> 17) * HID + lane], __int_as_float(v1.y) * g1);
        atomicAdd(&acc[(v2.x >> 17) * HID + lane], __int_as_float(v2.y) * g2);
        atomicAdd(&acc[(v3.x >> 17) * HID + lane], __int_as_float(v3.y) * g3);
    }
    for (; e < e1; e += 64) {
        int2 v = ebuf1[e];
        atomicAdd(&acc[(v.x >> 17) * HID + lane],
                  __int_as_float(v.y) * __half2float(hb[(v.x & 131071) * HID + lane]));
    }
    __syncthreads();
    // finish 1: x2 = dinv*(acc + self) + b2, back into acc
    for (int i = tid; i < BKT_NB * HID; i += 1024) {
        int node = k * BKT_NB + (i >> 4);
        if (node < N_NODES)
            acc[i] = dinv[node] * (acc[i] + __half2float(hb[node * HID + (i & 15)]))
                     + b2[i & 15];
    }
    __syncthreads();
    // finish 2: classifier + log_softmax, one 16-lane group per node
    for (int it = 0; it < BKT_NB / 64; ++it) {
        int nl = (tid >> 4) + it * 64;
        int node = k * BKT_NB + nl;
        if (node < N_NODES) {
            float l0 = bcs[lane];
            float l1 = bcs[lane + 16];
            float l2 = (lane < 8) ? bcs[lane + 32] : 0.0f;
            #pragma unroll
            for (int kk = 0; kk < HID; kk++) {
                float v = acc[nl * HID + kk];
                l0 += v * wcs[kk * NCLS + lane];
                l1 += v * wcs[kk * NCLS + lane + 16];
                if (lane < 8) l2 += v * wcs[kk * NCLS + lane + 32];
            }
            float m = fmaxf(l0, l1);
            if (lane < 8) m = fmaxf(m, l2);
            for (int o = 1; o < 16; o <<= 1) m = fmaxf(m, __shfl_xor(m, o, 64));
            float s = expf(l0 - m) + expf(l1 - m) + ((lane < 8) ? expf(l2 - m) : 0.0f);
            for (int o = 1; o < 16; o <<= 1) s += __shfl_xor(s, o, 64);
            float ls = logf(s) + m;
            out[node * NCLS + lane] = l0 - ls;
            out[node * NCLS + lane + 16] = l1 - ls;
            if (lane < 8) out[node * NCLS + lane + 32] = l2 - ls;
        }
    }
}

// ---- CSR aggregation (tier-2 path, fp16 tables) ----

__device__ __forceinline__ float edge_agg(const __half* __restrict__ h,
                                          const int2* __restrict__ edata,
                                          int e0, int e1, int lane, float acc) {
    int e = e0;
    for (; e + 8 <= e1; e += 8) {
        int2 d0 = edata[e];
        int2 d1 = edata[e + 1];
        int2 d2 = edata[e + 2];
        int2 d3 = edata[e + 3];
        int2 d4 = edata[e + 4];
        int2 d5 = edata[e + 5];
        int2 d6 = edata[e + 6];
        int2 d7 = edata[e + 7];
        float g0 = __half2float(h[d0.x * HID + lane]);
        float g1 = __half2float(h[d1.x * HID + lane]);
        float g2 = __half2float(h[d2.x * HID + lane]);
        float g3 = __half2float(h[d3.x * HID + lane]);
        float g4 = __half2float(h[d4.x * HID + lane]);
        float g5 = __half2float(h[d5.x * HID + lane]);
        float g6 = __half2float(h[d6.x * HID + lane]);
        float g7 = __half2float(h[d7.x * HID + lane]);
        acc += __int_as_float(d0.y) * g0;
        acc += __int_as_float(d1.y) * g1;
        acc += __int_as_float(d2.y) * g2;
        acc += __int_as_float(d3.y) * g3;
        acc += __int_as_float(d4.y) * g4;
        acc += __int_as_float(d5.y) * g5;
        acc += __int_as_float(d6.y) * g6;
        acc += __int_as_float(d7.y) * g7;
    }
    for (; e < e1; e++) {
        int2 ed = edata[e];
        acc += __int_as_float(ed.y) * __half2float(h[ed.x * HID + lane]);
    }
    return acc;
}

__global__ __launch_bounds__(256) void k_agg1(const __half* h1, const float* dinv,
                                              const int* offs, const int2* edata,
                                              const float* b1, const float* W2, __half* hb) {
    __shared__ float w2s[HID * HID];
    int tid = threadIdx.x;
    if (tid < HID * HID) w2s[tid] = W2[tid];
    __syncthreads();
    int lane = tid & 15;
    int node = blockIdx.x * 16 + (tid >> 4);
    int e0 = offs[node], e1 = offs[node + 1];
    float self = __half2float(h1[node * HID + lane]);
    float acc = edge_agg(h1, edata, e0, e1, lane, self);
    float d = dinv[node];
    acc = d * acc + b1[lane];
    acc = fmaxf(acc, 0.0f);
    int base = tid & 48;
    float h2 = 0.0f;
    for (int k = 0; k < HID; k++) {
        float v = __shfl(acc, base + k, 64);
        h2 += v * w2s[k * HID + lane];
    }
    hb[node * HID + lane] = __float2half(d * h2);
}

__global__ __launch_bounds__(256) void k_agg2(const __half* hb, const float* dinv,
                                              const int* offs, const int2* edata,
                                              const float* b2, const float* Wc,
                                              const float* bc, float* out) {
    __shared__ float wcs[HID * NCLS];
    __shared__ float bcs[NCLS];
    int tid = threadIdx.x;
    for (int i = tid; i < HID * NCLS; i += 256) wcs[i] = Wc[i];
    if (tid < NCLS) bcs[tid] = bc[tid];
    __syncthreads();
    int lane = tid & 15;
    int node = blockIdx.x * 16 + (tid >> 4);
    int e0 = offs[node], e1 = offs[node + 1];
    float self = __half2float(hb[node * HID + lane]);
    float acc = edge_agg(hb, edata, e0, e1, lane, self);
    acc = dinv[node] * acc + b2[lane];
    float l0 = bcs[lane];
    float l1 = bcs[lane + 16];
    float l2 = (lane < 8) ? bcs[lane + 32] : 0.0f;
    int base = tid & 48;
    for (int k = 0; k < HID; k++) {
        float v = __shfl(acc, base + k, 64);
        l0 += v * wcs[k * NCLS + lane];
        l1 += v * wcs[k * NCLS + lane + 16];
        if (lane < 8) l2 += v * wcs[k * NCLS + lane + 32];
    }
    float m = fmaxf(l0, l1);
    if (lane < 8) m = fmaxf(m, l2);
    for (int o = 1; o < 16; o <<= 1) m = fmaxf(m, __shfl_xor(m, o, 64));
    float s = expf(l0 - m) + expf(l1 - m) + ((lane < 8) ? expf(l2 - m) : 0.0f);
    for (int o = 1; o < 16; o <<= 1) s += __shfl_xor(s, o, 64);
    float ls = logf(s) + m;
    out[node * NCLS + lane] = l0 - ls;
    out[node * NCLS + lane + 16] = l1 - ls;
    if (lane < 8) out[node * NCLS + lane + 32] = l2 - ls;
}

// =================== tier-2: R5 atomic-CSR build ===================

__global__ __launch_bounds__(256) void k_init(int* cnt) {
    int i = blockIdx.x * 256 + threadIdx.x;
    if (i < N_NODES) cnt[i] = 0;
}

__global__ __launch_bounds__(256) void k_count(const int* col, int* cnt) {
    int e = blockIdx.x * 256 + threadIdx.x;
    atomicAdd(&cnt[col[e]], 1);
}

__global__ __launch_bounds__(1024) void k_scan1(const int* cnt, int* offs, int* bsum) {
    __shared__ int s[1024];
    int tid = threadIdx.x;
    int gid = blockIdx.x * 1024 + tid;
    int v = (gid < N_NODES) ? cnt[gid] : 0;
    s[tid] = v;
    __syncthreads();
    for (int o = 1; o < 1024; o <<= 1) {
        int t = (tid >= o) ? s[tid - o] : 0;
        __syncthreads();
        s[tid] += t;
        __syncthreads();
    }
    if (gid < N_NODES) offs[gid] = s[tid] - v;
    if (tid == 1023) bsum[blockIdx.x] = s[1023];
}

__global__ __launch_bounds__(128) void k_scan2(int* bsum) {
    __shared__ int s[128];
    int tid = threadIdx.x;
    int v = (tid < 98) ? bsum[tid] : 0;
    s[tid] = v;
    __syncthreads();
    for (int o = 1; o < 128; o <<= 1) {
        int t = (tid >= o) ? s[tid - o] : 0;
        __syncthreads();
        s[tid] += t;
        __syncthreads();
    }
    if (tid < 98) bsum[tid] = s[tid] - v;
}

__global__ __launch_bounds__(1024) void k_scan3(int* offs, int* cur, const int* bsum) {
    int tid = threadIdx.x;
    int gid = blockIdx.x * 1024 + tid;
    if (gid < N_NODES) {
        int o = offs[gid] + bsum[blockIdx.x];
        offs[gid] = o;
        cur[gid] = o;
    }
    if (gid == 0) offs[N_NODES] = N_EDGES;
}

__global__ __launch_bounds__(256) void k_scatter(const int* row, const int* col,
                                                 const float* w, int* cur, int2* edata) {
    int e = blockIdx.x * 256 + threadIdx.x;
    int r = row[e];
    int c = col[e];
    int p = atomicAdd(&cur[c], 1);
    edata[p] = make_int2(r, __float_as_int(w[e]));
}

__global__ __launch_bounds__(256) void k_deg_dinv(const int* offs, const int2* edata,
                                                  float* dinv) {
    int tid = threadIdx.x;
    int lane = tid & 15;
    int node = blockIdx.x * 16 + (tid >> 4);
    int e0 = offs[node], e1 = offs[node + 1];
    float s = 0.0f;
    for (int e = e0 + lane; e < e1; e += 16)
        s += __int_as_float(edata[e].y);
    for (int o = 1; o < 16; o <<= 1) s += __shfl_xor(s, o, 64);
    if (lane == 0) dinv[node] = 1.0f / sqrtf(1.0f + s);
}

// =================== tier-3: edge-atomic fallback (+shared init/dinv) ===================

__global__ __launch_bounds__(256) void k_init_deg(float* deg) {
    int i = blockIdx.x * 256 + threadIdx.x;
    if (i < N_NODES) deg[i] = 1.0f;
}

__global__ __launch_bounds__(256) void k_deg_only(const int* col, const float* w, float* deg) {
    int e = blockIdx.x * 256 + threadIdx.x;
    atomicAdd(&deg[col[e]], w[e]);
}

__global__ __launch_bounds__(256) void k_dinv(float* deg) {
    int i = blockIdx.x * 256 + threadIdx.x;
    if (i < N_NODES) {
        float d = deg[i];
        deg[i] = (d > 0.0f) ? 1.0f / sqrtf(d) : 0.0f;
    }
}

__global__ __launch_bounds__(256) void k_self(const float* dinv, const float* h, float* agg) {
    int i = blockIdx.x * 256 + threadIdx.x;
    float d = dinv[i >> 4];
    agg[i] = d * d * h[i];
}

__global__ __launch_bounds__(256) void k_edge_atomic(const int* row, const int* col,
                                                     const float* w, const float* dinv,
                                                     const float* h, float* agg) {
    int gid = blockIdx.x * 256 + threadIdx.x;
    int e = gid >> 4, lane = gid & 15;
    int r = row[e], c = col[e];
    float nrm = dinv[r] * w[e] * dinv[c];
    atomicAdd(&agg[c * HID + lane], nrm * h[r * HID + lane]);
}

__global__ __launch_bounds__(256) void k_bias_relu_gemm2(const float* agg, const float* b1,
                                                         const float* W2, float* out2) {
    __shared__ float w2s[HID * HID];
    int tid = threadIdx.x;
    if (tid < HID * HID) w2s[tid] = W2[tid];
    __syncthreads();
    int lane = tid & 15;
    int node = blockIdx.x * 16 + (tid >> 4);
    float acc = fmaxf(agg[node * HID + lane] + b1[lane], 0.0f);
    int base = tid & 48;
    float h2 = 0.0f;
    for (int k = 0; k < HID; k++) {
        float v = __shfl(acc, base + k, 64);
        h2 += v * w2s[k * HID + lane];
    }
    out2[node * HID + lane] = h2;
}

__global__ __launch_bounds__(256) void k_final(const float* agg, const float* b2,
                                               const float* Wc, const float* bc, float* out) {
    __shared__ float wcs[HID * NCLS];
    __shared__ float bcs[NCLS];
    int tid = threadIdx.x;
    for (int i = tid; i < HID * NCLS; i += 256) wcs[i] = Wc[i];
    if (tid < NCLS) bcs[tid] = bc[tid];
    __syncthreads();
    int lane = tid & 15;
    int node = blockIdx.x * 16 + (tid >> 4);
    float acc = agg[node * HID + lane] + b2[lane];
    float l0 = bcs[lane];
    float l1 = bcs[lane + 16];
    float l2 = (lane < 8) ? bcs[lane + 32] : 0.0f;
    int base = tid & 48;
    for (int k = 0; k < HID; k++) {
        float v = __shfl(acc, base + k, 64);
        l0 += v * wcs[k * NCLS + lane];
        l1 += v * wcs[k * NCLS + lane + 16];
        if (lane < 8) l2 += v * wcs[k * NCLS + lane + 32];
    }
    float m = fmaxf(l0, l1);
    if (lane < 8) m = fmaxf(m, l2);
    for (int o = 1; o < 16; o <<= 1) m = fmaxf(m, __shfl_xor(m, o, 64));
    float s = expf(l0 - m) + expf(l1 - m) + ((lane < 8) ? expf(l2 - m) : 0.0f);
    for (int o = 1; o < 16; o <<= 1) s += __shfl_xor(s, o, 64);
    float ls = logf(s) + m;
    out[node * NCLS + lane] = l0 - ls;
    out[node * NCLS + lane + 16] = l1 - ls;
    if (lane < 8) out[node * NCLS + lane + 32] = l2 - ls;
}

extern "C" void kernel_launch(void* const* d_in, const int* in_sizes, int n_in,
                              void* d_out, int out_size, void* d_ws, size_t ws_size,
                              hipStream_t stream) {
    const float* z     = (const float*)d_in[0];
    const int*   eidx  = (const int*)d_in[1];
    const float* eattr = (const float*)d_in[2];
    const float* W1    = (const float*)d_in[3];
    const float* b1    = (const float*)d_in[4];
    const float* W2    = (const float*)d_in[5];
    const float* b2    = (const float*)d_in[6];
    const float* Wc    = (const float*)d_in[7];
    const float* bc    = (const float*)d_in[8];
    float* out = (float*)d_out;

    char* ws = (char*)d_ws;
    const int* rowp = eidx;
    const int* colp = eidx + N_EDGES;

    int nblk = (N_NODES + 255) / 256;               // 391
    int eblk = N_EDGES / 256;                       // 25000
    int sblk = (N_NODES + 1023) / 1024;             // 98
    int gblk = (N_NODES + 63) / 64;                 // 1563
    int ablk = N_NODES / 16;                        // 6250
    int fblk = (N_NODES * HID) / 256;               // 6250
    int exblk = (N_EDGES * HID) / 256;              // 400000

    if (ws_size >= (size_t)WS_T1_NEED) {
        // ---------- tier-1: bucket-major build + LDS-accumulate agg ----------
        int*    cbase  = (int*)(ws + OFF_CB);
        int*    tot    = (int*)(ws + OFF_TOT);
        float*  dinv   = (float*)(ws + OFF_DINV);   // deg, then rsqrt in place
        int*    histc  = (int*)(ws + OFF_HISTC);
        int*    histex = (int*)(ws + OFF_HISTEX);
        int2*   ebuf1  = (int2*)(ws + OFF_EBUF1);
        __half* h1     = (__half*)(ws + OFF_H1);
        __half* hb     = (__half*)(ws + OFF_HB);

        k_init_deg<<<nblk, 256, 0, stream>>>(dinv);              // deg = 1 (self loop)
        k_hist<<<B_PART, 1024, 0, stream>>>(colp, histc);
        k_colscan<<<K_BKT, 1024, 0, stream>>>(histc, histex, tot);
        k_basescan<<<1, 1024, 0, stream>>>(tot, cbase);
        k_partition<<<B_PART, 1024, 0, stream>>>(rowp, colp, eattr, histc, histex,
                                                 cbase, ebuf1, dinv);
        k_dinv<<<nblk, 256, 0, stream>>>(dinv);                  // deg -> rsqrt
        k_gemm1<<<gblk, 256, 0, stream>>>(z, W1, h1, dinv);
        k_aggm1<<<K_BKT, 1024, 0, stream>>>(ebuf1, cbase, h1, dinv, b1, W2, hb);
        k_aggm2<<<K_BKT, 1024, 0, stream>>>(ebuf1, cbase, hb, dinv, b2, Wc, bc, out);
    } else if (ws_size >= (size_t)WS_T2_NEED) {
        // ---------- tier-2: atomic-CSR path (R5) ----------
        float*  dinv = (float*)(ws + T2_DINV);
        int*    cnt  = (int*)(ws + T2_CNT);
        int*    offs = (int*)(ws + T2_OFFS);
        int2*   edat = (int2*)(ws + T2_EDATA);
        __half* h1   = (__half*)(ws + T2_H1);
        __half* hb   = (__half*)(ws + T2_HB);
        int*    bsum = (int*)(ws + T2_BSUM);

        k_init<<<nblk, 256, 0, stream>>>(cnt);
        k_count<<<eblk, 256, 0, stream>>>(colp, cnt);
        k_scan1<<<sblk, 1024, 0, stream>>>(cnt, offs, bsum);
        k_scan2<<<1, 128, 0, stream>>>(bsum);
        k_scan3<<<sblk, 1024, 0, stream>>>(offs, cnt, bsum);
        k_scatter<<<eblk, 256, 0, stream>>>(rowp, colp, eattr, cnt, edat);
        k_deg_dinv<<<ablk, 256, 0, stream>>>(offs, edat, dinv);
        k_gemm1<<<gblk, 256, 0, stream>>>(z, W1, h1, dinv);
        k_agg1<<<ablk, 256, 0, stream>>>(h1, dinv, offs, edat, b1, W2, hb);
        k_agg2<<<ablk, 256, 0, stream>>>(hb, dinv, offs, edat, b2, Wc, bc, out);
    } else {
        // ---------- tier-3: edge-atomic fallback (f32 throughout) ----------
        float* deg = (float*)(ws + OFF3_DEG);
        float* h1  = (float*)(ws + OFF3_H1);
        float* hb  = (float*)(ws + OFF3_HB);

        k_init_deg<<<nblk, 256, 0, stream>>>(deg);
        k_deg_only<<<eblk, 256, 0, stream>>>(colp, eattr, deg);
        k_dinv<<<nblk, 256, 0, stream>>>(deg);
        k_gemm1f<<<gblk, 256, 0, stream>>>(z, W1, hb, nullptr);
        k_self<<<fblk, 256, 0, stream>>>(deg, hb, h1);
        k_edge_atomic<<<exblk, 256, 0, stream>>>(rowp, colp, eattr, deg, hb, h1);
        k_bias_relu_gemm2<<<ablk, 256, 0, stream>>>(h1, b1, W2, hb);
        k_self<<<fblk, 256, 0, stream>>>(deg, hb, h1);
        k_edge_atomic<<<exblk, 256, 0, stream>>>(rowp, colp, eattr, deg, hb, h1);
        k_final<<<ablk, 256, 0, stream>>>(h1, b2, Wc, bc, out);
    }
}

// Round 7
// 400.893 us; speedup vs baseline: 4.6351x; 4.6351x over previous
//
#include <hip/hip_runtime.h>
#include <hip/hip_bf16.h>
#include <hip/hip_fp16.h>

// GCN inference: conv1(128->16)+ReLU -> conv2(16->16) -> linear(16->40) -> log_softmax
// R14 post-mortem: FALSIFIER FIRED. plain atomicAdd(__shared__ f32) = 688us,
// identical to R10's unsafeAtomicAdd (686us). LDS f32 atomic accumulation is
// structurally ~100x slow on gfx950/this toolchain regardless of intrinsic.
// PERMANENT LESSON: sorted CSR + register accumulation only. Reverted to R13.
// R15: apply R11's LDS-staging medicine to bucketsort itself:
//  - 782 buckets (col>>7, 128 nodes): 2x width, half per-block work
//  - pass B scatters to led[9216] (73.7KB LDS, >64KB OK on gfx950) at LOCAL
//    positions, then coalesced linear writeout -> kills the atomic->scattered-
//    store chain and the 1.4x write amplification. Fallback to direct scatter
//    if bucket > capacity (mean 8192, +11 sigma).
//  - k_hist int4 col loads.

#define N_NODES 100000
#define N_EDGES 6400000
#define IN_DIM  128
#define HID     16
#define NCLS    40

#define K_BKT    782         // buckets = col>>7, 128 nodes each (last: 32)
#define BKT_SH   7
#define BKT_NB   128         // nodes per bucket
#define BKT_MASK 127
#define B_PART   1000        // histogram/partition blocks
#define CHUNK    6400        // edges per partition block (fits LDS staging)
#define BS_CAP   9216        // bucketsort LDS staging capacity (edges)

// ---- tier-1 workspace layout (bytes) ----
#define OFF_CB    0          // int[783] bucket bases
#define OFF_TOT   4096       // int[782] bucket totals
#define OFF_DINV  8192       // float[N]
#define OFF_OFFS  408192     // int[N+1]
#define OFF_EBUF1 808256     // int2[E] bucket-major edges (dead after bucketsort)
#define OFF_EDATA 52008256   // int2[E] final CSR (row, w) -- ends 103,208,256
#define OFF_HIST   OFF_EDATA               // int[1000*782] (dead before bucketsort)
#define OFF_HISTEX (OFF_EDATA + 3128000)   // int[1000*782]
#define WS_T1_NEED 103600000
// h1/hb (fp16, 3.2MB each) overlay the dead ebuf1 region:
#define OFF_H1    OFF_EBUF1
#define OFF_HB    (OFF_EBUF1 + 3200000)

// ---- tier-2 workspace layout (R5 atomic-CSR path, fp16 h) ----
#define T2_DINV  0
#define T2_CNT   400128
#define T2_OFFS  800256
#define T2_EDATA 1200384
#define T2_H1    52400384
#define T2_HB    58800384
#define T2_BSUM  65200384
#define WS_T2_NEED 65210000

// ---- tier-3 fallback layout ----
#define OFF3_DEG 0
#define OFF3_H1  400128
#define OFF3_HB  6800384

// =================== tier-1: deterministic CSR build ===================

__global__ __launch_bounds__(1024) void k_hist(const int* col, int* histcnt) {
    __shared__ int h[K_BKT];
    int t = threadIdx.x;
    if (t < K_BKT) h[t] = 0;
    __syncthreads();
    int b = blockIdx.x;
    const int4* c4 = (const int4*)(col + b * CHUNK);  // CHUNK*4B chunks are 16B-aligned
    for (int i = t; i < CHUNK / 4; i += 1024) {
        int4 c = c4[i];
        atomicAdd(&h[c.x >> BKT_SH], 1);              // LDS int atomic: fast path
        atomicAdd(&h[c.y >> BKT_SH], 1);
        atomicAdd(&h[c.z >> BKT_SH], 1);
        atomicAdd(&h[c.w >> BKT_SH], 1);
    }
    __syncthreads();
    if (t < K_BKT) histcnt[b * K_BKT + t] = h[t];
}

// one block per bucket k: exclusive-scan histcnt[.][k] over the 1000 blocks
// into histex (histcnt preserved -- partition needs local counts).
__global__ __launch_bounds__(1024) void k_colscan(const int* histcnt, int* histex, int* tot) {
    __shared__ int s[1024];
    int t = threadIdx.x;
    int k = blockIdx.x;
    int v = (t < B_PART) ? histcnt[t * K_BKT + k] : 0;
    s[t] = v;
    __syncthreads();
    for (int o = 1; o < 1024; o <<= 1) {
        int a = (t >= o) ? s[t - o] : 0;
        __syncthreads();
        s[t] += a;
        __syncthreads();
    }
    if (t < B_PART) histex[t * K_BKT + k] = s[t] - v;  // exclusive
    if (t == 0) tot[k] = s[B_PART - 1];                // inclusive total
}

__global__ __launch_bounds__(1024) void k_basescan(const int* tot, int* cbase) {
    __shared__ int s[1024];
    int t = threadIdx.x;
    int v = (t < K_BKT) ? tot[t] : 0;
    s[t] = v;
    __syncthreads();
    for (int o = 1; o < 1024; o <<= 1) {
        int a = (t >= o) ? s[t - o] : 0;
        __syncthreads();
        s[t] += a;
        __syncthreads();
    }
    if (t < K_BKT) cbase[t] = s[t] - v;               // exclusive
    if (t == 0) cbase[K_BKT] = N_EDGES;
}

// LDS-staged partition: counting-sort the block's chunk in LDS, then write
// bucket-segments to global in slot order (coalesced runs).
// packed = row | (col_local<<17)   (col_local 7 bits; row < 2^17)
__global__ __launch_bounds__(1024) void k_partition(const int* row, const int* col,
                                                    const float* w, const int* histcnt,
                                                    const int* histex, const int* cbase,
                                                    int2* ebuf1) {
    __shared__ int2 led[CHUNK];          // 51.2KB staged edges (local sorted order)
    __shared__ int  sscan[1024];
    __shared__ int  lbase[K_BKT + 1];    // local exclusive offsets
    __shared__ int  gofs[K_BKT];         // global_base - local_base per bucket
    __shared__ int  cur[K_BKT];
    int t = threadIdx.x;
    int b = blockIdx.x;
    // local exclusive scan of this block's bucket counts
    int v = (t < K_BKT) ? histcnt[b * K_BKT + t] : 0;
    sscan[t] = v;
    __syncthreads();
    for (int o = 1; o < 1024; o <<= 1) {
        int a = (t >= o) ? sscan[t - o] : 0;
        __syncthreads();
        sscan[t] += a;
        __syncthreads();
    }
    if (t < K_BKT) {
        int ex = sscan[t] - v;
        lbase[t] = ex;
        cur[t] = ex;
        gofs[t] = cbase[t] + histex[b * K_BKT + t] - ex;
    }
    if (t == 0) lbase[K_BKT] = CHUNK;
    __syncthreads();
    // local scatter into LDS (2x unrolled; LDS store latency trivial)
    int end = (b + 1) * CHUNK;
    int e = b * CHUNK + t;
    for (; e + 1024 < end; e += 2048) {
        int c0 = col[e],  c1 = col[e + 1024];
        int r0 = row[e],  r1 = row[e + 1024];
        float w0 = w[e],  w1 = w[e + 1024];
        int p0 = atomicAdd(&cur[c0 >> BKT_SH], 1);
        int p1 = atomicAdd(&cur[c1 >> BKT_SH], 1);
        led[p0] = make_int2(r0 | ((c0 & BKT_MASK) << 17), __float_as_int(w0));
        led[p1] = make_int2(r1 | ((c1 & BKT_MASK) << 17), __float_as_int(w1));
    }
    for (; e < end; e += 1024) {
        int c = col[e];
        int p = atomicAdd(&cur[c >> BKT_SH], 1);
        led[p] = make_int2(row[e] | ((c & BKT_MASK) << 17), __float_as_int(w[e]));
    }
    __syncthreads();
    // write-out in slot order -> coalesced runs per bucket segment
    for (int i = t; i < CHUNK; i += 1024) {
        int2 ed = led[i];
        int lo = 0, hi = K_BKT;          // find k: lbase[k] <= i < lbase[k+1]
        while (hi - lo > 1) {
            int mid = (lo + hi) >> 1;
            if (lbase[mid] <= i) lo = mid; else hi = mid;
        }
        ebuf1[gofs[lo] + i] = ed;
    }
}

// per-bucket fine counting sort (128 local nodes) -> edata CSR; also offs + dinv.
// Pass B scatters into LDS at LOCAL positions, then writes out coalesced.
__global__ __launch_bounds__(1024) void k_bucketsort(const int2* ebuf1, const int* cbase,
                                                     int2* edata, int* offs, float* dinv) {
    __shared__ int2  led[BS_CAP];        // 73.7KB sorted staging
    __shared__ int   cnt[BKT_NB];
    __shared__ float degw[BKT_NB];
    __shared__ int   sc[BKT_NB];
    __shared__ int   cur[BKT_NB];
    int t = threadIdx.x;
    int k = blockIdx.x;
    if (t < BKT_NB) { cnt[t] = 0; degw[t] = 0.0f; }
    __syncthreads();
    int e0 = cbase[k], e1 = cbase[k + 1];
    // pass A: local histogram + weighted degree (4x unrolled, fire-and-forget)
    int e = e0 + t;
    for (; e + 3072 < e1; e += 4096) {
        int2 v0 = ebuf1[e];
        int2 v1 = ebuf1[e + 1024];
        int2 v2 = ebuf1[e + 2048];
        int2 v3 = ebuf1[e + 3072];
        int a0 = v0.x >> 17, a1 = v1.x >> 17, a2 = v2.x >> 17, a3 = v3.x >> 17;
        atomicAdd(&cnt[a0], 1); atomicAdd(&degw[a0], __int_as_float(v0.y));
        atomicAdd(&cnt[a1], 1); atomicAdd(&degw[a1], __int_as_float(v1.y));
        atomicAdd(&cnt[a2], 1); atomicAdd(&degw[a2], __int_as_float(v2.y));
        atomicAdd(&cnt[a3], 1); atomicAdd(&degw[a3], __int_as_float(v3.y));
    }
    for (; e < e1; e += 1024) {
        int2 v = ebuf1[e];
        int cl = v.x >> 17;
        atomicAdd(&cnt[cl], 1);
        atomicAdd(&degw[cl], __int_as_float(v.y));
    }
    __syncthreads();
    int c0 = (t < BKT_NB) ? cnt[t] : 0;
    if (t < BKT_NB) sc[t] = c0;
    __syncthreads();
    for (int o = 1; o < BKT_NB; o <<= 1) {            // inclusive scan of 128
        int a = (t < BKT_NB && t >= o) ? sc[t - o] : 0;
        __syncthreads();
        if (t < BKT_NB) sc[t] += a;
        __syncthreads();
    }
    // exclusive LOCAL offsets; emit offs + dinv for this bucket's nodes
    if (t < BKT_NB) {
        int ex = sc[t] - c0;
        cur[t] = ex;                                  // local position base
        int node = k * BKT_NB + t;
        if (node < N_NODES) {
            offs[node] = e0 + ex;
            dinv[node] = rsqrtf(1.0f + degw[t]);
        }
    }
    if (k == 0 && t == 0) offs[N_NODES] = N_EDGES;
    __syncthreads();
    int len = e1 - e0;
    if (len <= BS_CAP) {
        // pass B: scatter into LDS at local sorted positions (4x unrolled)
        e = e0 + t;
        for (; e + 3072 < e1; e += 4096) {
            int2 v0 = ebuf1[e];
            int2 v1 = ebuf1[e + 1024];
            int2 v2 = ebuf1[e + 2048];
            int2 v3 = ebuf1[e + 3072];
            int p0 = atomicAdd(&cur[v0.x >> 17], 1);
            int p1 = atomicAdd(&cur[v1.x >> 17], 1);
            int p2 = atomicAdd(&cur[v2.x >> 17], 1);
            int p3 = atomicAdd(&cur[v3.x >> 17], 1);
            led[p0] = make_int2(v0.x & 131071, v0.y);
            led[p1] = make_int2(v1.x & 131071, v1.y);
            led[p2] = make_int2(v2.x & 131071, v2.y);
            led[p3] = make_int2(v3.x & 131071, v3.y);
        }
        for (; e < e1; e += 1024) {
            int2 v = ebuf1[e];
            int p = atomicAdd(&cur[v.x >> 17], 1);
            led[p] = make_int2(v.x & 131071, v.y);
        }
        __syncthreads();
        // coalesced linear writeout (consecutive lanes -> consecutive addrs)
        for (int i = t; i < len; i += 1024)
            edata[e0 + i] = led[i];
    } else {
        // fallback (capacity exceeded; statistically never at +11 sigma):
        // direct scatter using local positions
        e = e0 + t;
        for (; e < e1; e += 1024) {
            int2 v = ebuf1[e];
            int p = atomicAdd(&cur[v.x >> 17], 1);
            edata[e0 + p] = make_int2(v.x & 131071, v.y);
        }
    }
}

// =================== shared compute kernels ===================

// h1 = fp16(dinv[node] * (z @ W1)) -- fp16 so gather table (3.2MB) is L2-resident
__global__ __launch_bounds__(256) void k_gemm1(const float* z, const float* W1,
                                               __half* h1, const float* dinv) {
    __shared__ float w1s[IN_DIM * HID];
    __shared__ float zs[64 * 132];
    int tid = threadIdx.x;
    for (int i = tid; i < IN_DIM * HID / 4; i += 256)
        ((float4*)w1s)[i] = ((const float4*)W1)[i];
    int nodeBase = blockIdx.x * 64;
    for (int i = tid; i < 64 * 32; i += 256) {
        int nl = i >> 5, kq = i & 31;
        int node = nodeBase + nl;
        float4 v = (node < N_NODES) ? ((const float4*)z)[node * 32 + kq]
                                    : make_float4(0.f, 0.f, 0.f, 0.f);
        *(float4*)&zs[nl * 132 + kq * 4] = v;
    }
    __syncthreads();
    int nl = tid >> 2;
    int jb = (tid & 3) * 4;
    int node = nodeBase + nl;
    float4 acc = make_float4(0.f, 0.f, 0.f, 0.f);
    for (int k = 0; k < IN_DIM; k++) {
        float s = zs[nl * 132 + k];
        float4 wv = *(const float4*)&w1s[k * HID + jb];
        acc.x += s * wv.x; acc.y += s * wv.y; acc.z += s * wv.z; acc.w += s * wv.w;
    }
    if (node < N_NODES) {
        float dv = dinv ? dinv[node] : 1.0f;
        union { __half2 h2[2]; uint2 u; } pk;
        pk.h2[0] = __floats2half2_rn(acc.x * dv, acc.y * dv);
        pk.h2[1] = __floats2half2_rn(acc.z * dv, acc.w * dv);
        ((uint2*)h1)[node * 4 + (tid & 3)] = pk.u;    // 8B store: 4 halves
    }
}

// f32-output variant for tier-3
__global__ __launch_bounds__(256) void k_gemm1f(const float* z, const float* W1, float* h1,
                                                const float* dinv) {
    __shared__ float w1s[IN_DIM * HID];
    __shared__ float zs[64 * 132];
    int tid = threadIdx.x;
    for (int i = tid; i < IN_DIM * HID / 4; i += 256)
        ((float4*)w1s)[i] = ((const float4*)W1)[i];
    int nodeBase = blockIdx.x * 64;
    for (int i = tid; i < 64 * 32; i += 256) {
        int nl = i >> 5, kq = i & 31;
        int node = nodeBase + nl;
        float4 v = (node < N_NODES) ? ((const float4*)z)[node * 32 + kq]
                                    : make_float4(0.f, 0.f, 0.f, 0.f);
        *(float4*)&zs[nl * 132 + kq * 4] = v;
    }
    __syncthreads();
    int nl = tid >> 2;
    int jb = (tid & 3) * 4;
    int node = nodeBase + nl;
    float4 acc = make_float4(0.f, 0.f, 0.f, 0.f);
    for (int k = 0; k < IN_DIM; k++) {
        float s = zs[nl * 132 + k];
        float4 wv = *(const float4*)&w1s[k * HID + jb];
        acc.x += s * wv.x; acc.y += s * wv.y; acc.z += s * wv.z; acc.w += s * wv.w;
    }
    if (node < N_NODES) {
        float dv = dinv ? dinv[node] : 1.0f;
        acc.x *= dv; acc.y *= dv; acc.z *= dv; acc.w *= dv;
        ((float4*)h1)[node * 4 + (tid & 3)] = acc;
    }
}

// 8x-unrolled CSR edge aggregation over fp16 feature table
__device__ __forceinline__ float edge_agg(const __half* __restrict__ h,
                                          const int2* __restrict__ edata,
                                          int e0, int e1, int lane, float acc) {
    int e = e0;
    for (; e + 8 <= e1; e += 8) {
        int2 d0 = edata[e];
        int2 d1 = edata[e + 1];
        int2 d2 = edata[e + 2];
        int2 d3 = edata[e + 3];
        int2 d4 = edata[e + 4];
        int2 d5 = edata[e + 5];
        int2 d6 = edata[e + 6];
        int2 d7 = edata[e + 7];
        float g0 = __half2float(h[d0.x * HID + lane]);
        float g1 = __half2float(h[d1.x * HID + lane]);
        float g2 = __half2float(h[d2.x * HID + lane]);
        float g3 = __half2float(h[d3.x * HID + lane]);
        float g4 = __half2float(h[d4.x * HID + lane]);
        float g5 = __half2float(h[d5.x * HID + lane]);
        float g6 = __half2float(h[d6.x * HID + lane]);
        float g7 = __half2float(h[d7.x * HID + lane]);
        acc += __int_as_float(d0.y) * g0;
        acc += __int_as_float(d1.y) * g1;
        acc += __int_as_float(d2.y) * g2;
        acc += __int_as_float(d3.y) * g3;
        acc += __int_as_float(d4.y) * g4;
        acc += __int_as_float(d5.y) * g5;
        acc += __int_as_float(d6.y) * g6;
        acc += __int_as_float(d7.y) * g7;
    }
    for (; e < e1; e++) {
        int2 ed = edata[e];
        acc += __int_as_float(ed.y) * __half2float(h[ed.x * HID + lane]);
    }
    return acc;
}

// conv1 aggregate (+b1, ReLU), fused h2 = x1 @ W2; hb = fp16(dinv * h2)
__global__ __launch_bounds__(256) void k_agg1(const __half* h1, const float* dinv,
                                              const int* offs, const int2* edata,
                                              const float* b1, const float* W2, __half* hb) {
    __shared__ float w2s[HID * HID];
    int tid = threadIdx.x;
    if (tid < HID * HID) w2s[tid] = W2[tid];
    __syncthreads();
    int lane = tid & 15;
    int node = blockIdx.x * 16 + (tid >> 4);
    int e0 = offs[node], e1 = offs[node + 1];
    float self = __half2float(h1[node * HID + lane]);
    float acc = edge_agg(h1, edata, e0, e1, lane, self);
    float d = dinv[node];
    acc = d * acc + b1[lane];
    acc = fmaxf(acc, 0.0f);
    int base = tid & 48;
    float h2 = 0.0f;
    for (int k = 0; k < HID; k++) {
        float v = __shfl(acc, base + k, 64);
        h2 += v * w2s[k * HID + lane];
    }
    hb[node * HID + lane] = __float2half(d * h2);
}

// conv2 aggregate (+b2), classifier (16->40) + log_softmax
__global__ __launch_bounds__(256) void k_agg2(const __half* hb, const float* dinv,
                                              const int* offs, const int2* edata,
                                              const float* b2, const float* Wc,
                                              const float* bc, float* out) {
    __shared__ float wcs[HID * NCLS];
    __shared__ float bcs[NCLS];
    int tid = threadIdx.x;
    for (int i = tid; i < HID * NCLS; i += 256) wcs[i] = Wc[i];
    if (tid < NCLS) bcs[tid] = bc[tid];
    __syncthreads();
    int lane = tid & 15;
    int node = blockIdx.x * 16 + (tid >> 4);
    int e0 = offs[node], e1 = offs[node + 1];
    float self = __half2float(hb[node * HID + lane]);
    float acc = edge_agg(hb, edata, e0, e1, lane, self);
    acc = dinv[node] * acc + b2[lane];
    float l0 = bcs[lane];
    float l1 = bcs[lane + 16];
    float l2 = (lane < 8) ? bcs[lane + 32] : 0.0f;
    int base = tid & 48;
    for (int k = 0; k < HID; k++) {
        float v = __shfl(acc, base + k, 64);
        l0 += v * wcs[k * NCLS + lane];
        l1 += v * wcs[k * NCLS + lane + 16];
        if (lane < 8) l2 += v * wcs[k * NCLS + lane + 32];
    }
    float m = fmaxf(l0, l1);
    if (lane < 8) m = fmaxf(m, l2);
    for (int o = 1; o < 16; o <<= 1) m = fmaxf(m, __shfl_xor(m, o, 64));
    float s = expf(l0 - m) + expf(l1 - m) + ((lane < 8) ? expf(l2 - m) : 0.0f);
    for (int o = 1; o < 16; o <<= 1) s += __shfl_xor(s, o, 64);
    float ls = logf(s) + m;
    out[node * NCLS + lane] = l0 - ls;
    out[node * NCLS + lane + 16] = l1 - ls;
    if (lane < 8) out[node * NCLS + lane + 32] = l2 - ls;
}

// =================== tier-2: R5 atomic-CSR build ===================

__global__ __launch_bounds__(256) void k_init(int* cnt) {
    int i = blockIdx.x * 256 + threadIdx.x;
    if (i < N_NODES) cnt[i] = 0;
}

__global__ __launch_bounds__(256) void k_count(const int* col, int* cnt) {
    int e = blockIdx.x * 256 + threadIdx.x;
    atomicAdd(&cnt[col[e]], 1);
}

__global__ __launch_bounds__(1024) void k_scan1(const int* cnt, int* offs, int* bsum) {
    __shared__ int s[1024];
    int tid = threadIdx.x;
    int gid = blockIdx.x * 1024 + tid;
    int v = (gid < N_NODES) ? cnt[gid] : 0;
    s[tid] = v;
    __syncthreads();
    for (int o = 1; o < 1024; o <<= 1) {
        int t = (tid >= o) ? s[tid - o] : 0;
        __syncthreads();
        s[tid] += t;
        __syncthreads();
    }
    if (gid < N_NODES) offs[gid] = s[tid] - v;
    if (tid == 1023) bsum[blockIdx.x] = s[1023];
}

__global__ __launch_bounds__(128) void k_scan2(int* bsum) {
    __shared__ int s[128];
    int tid = threadIdx.x;
    int v = (tid < 98) ? bsum[tid] : 0;
    s[tid] = v;
    __syncthreads();
    for (int o = 1; o < 128; o <<= 1) {
        int t = (tid >= o) ? s[tid - o] : 0;
        __syncthreads();
        s[tid] += t;
        __syncthreads();
    }
    if (tid < 98) bsum[tid] = s[tid] - v;
}

__global__ __launch_bounds__(1024) void k_scan3(int* offs, int* cur, const int* bsum) {
    int tid = threadIdx.x;
    int gid = blockIdx.x * 1024 + tid;
    if (gid < N_NODES) {
        int o = offs[gid] + bsum[blockIdx.x];
        offs[gid] = o;
        cur[gid] = o;
    }
    if (gid == 0) offs[N_NODES] = N_EDGES;
}

__global__ __launch_bounds__(256) void k_scatter(const int* row, const int* col,
                                                 const float* w, int* cur, int2* edata) {
    int e = blockIdx.x * 256 + threadIdx.x;
    int r = row[e];
    int c = col[e];
    int p = atomicAdd(&cur[c], 1);
    edata[p] = make_int2(r, __float_as_int(w[e]));
}

__global__ __launch_bounds__(256) void k_deg_dinv(const int* offs, const int2* edata,
                                                  float* dinv) {
    int tid = threadIdx.x;
    int lane = tid & 15;
    int node = blockIdx.x * 16 + (tid >> 4);
    int e0 = offs[node], e1 = offs[node + 1];
    float s = 0.0f;
    for (int e = e0 + lane; e < e1; e += 16)
        s += __int_as_float(edata[e].y);
    for (int o = 1; o < 16; o <<= 1) s += __shfl_xor(s, o, 64);
    if (lane == 0) dinv[node] = 1.0f / sqrtf(1.0f + s);
}

// =================== tier-3: edge-atomic fallback ===================

__global__ __launch_bounds__(256) void k_init_deg(float* deg) {
    int i = blockIdx.x * 256 + threadIdx.x;
    if (i < N_NODES) deg[i] = 1.0f;
}

__global__ __launch_bounds__(256) void k_deg_only(const int* col, const float* w, float* deg) {
    int e = blockIdx.x * 256 + threadIdx.x;
    atomicAdd(&deg[col[e]], w[e]);
}

__global__ __launch_bounds__(256) void k_dinv(float* deg) {
    int i = blockIdx.x * 256 + threadIdx.x;
    if (i < N_NODES) {
        float d = deg[i];
        deg[i] = (d > 0.0f) ? 1.0f / sqrtf(d) : 0.0f;
    }
}

__global__ __launch_bounds__(256) void k_self(const float* dinv, const float* h, float* agg) {
    int i = blockIdx.x * 256 + threadIdx.x;
    float d = dinv[i >> 4];
    agg[i] = d * d * h[i];
}

__global__ __launch_bounds__(256) void k_edge_atomic(const int* row, const int* col,
                                                     const float* w, const float* dinv,
                                                     const float* h, float* agg) {
    int gid = blockIdx.x * 256 + threadIdx.x;
    int e = gid >> 4, lane = gid & 15;
    int r = row[e], c = col[e];
    float nrm = dinv[r] * w[e] * dinv[c];
    atomicAdd(&agg[c * HID + lane], nrm * h[r * HID + lane]);
}

__global__ __launch_bounds__(256) void k_bias_relu_gemm2(const float* agg, const float* b1,
                                                         const float* W2, float* out2) {
    __shared__ float w2s[HID * HID];
    int tid = threadIdx.x;
    if (tid < HID * HID) w2s[tid] = W2[tid];
    __syncthreads();
    int lane = tid & 15;
    int node = blockIdx.x * 16 + (tid >> 4);
    float acc = fmaxf(agg[node * HID + lane] + b1[lane], 0.0f);
    int base = tid & 48;
    float h2 = 0.0f;
    for (int k = 0; k < HID; k++) {
        float v = __shfl(acc, base + k, 64);
        h2 += v * w2s[k * HID + lane];
    }
    out2[node * HID + lane] = h2;
}

__global__ __launch_bounds__(256) void k_final(const float* agg, const float* b2,
                                               const float* Wc, const float* bc, float* out) {
    __shared__ float wcs[HID * NCLS];
    __shared__ float bcs[NCLS];
    int tid = threadIdx.x;
    for (int i = tid; i < HID * NCLS; i += 256) wcs[i] = Wc[i];
    if (tid < NCLS) bcs[tid] = bc[tid];
    __syncthreads();
    int lane = tid & 15;
    int node = blockIdx.x * 16 + (tid >> 4);
    float acc = agg[node * HID + lane] + b2[lane];
    float l0 = bcs[lane];
    float l1 = bcs[lane + 16];
    float l2 = (lane < 8) ? bcs[lane + 32] : 0.0f;
    int base = tid & 48;
    for (int k = 0; k < HID; k++) {
        float v = __shfl(acc, base + k, 64);
        l0 += v * wcs[k * NCLS + lane];
        l1 += v * wcs[k * NCLS + lane + 16];
        if (lane < 8) l2 += v * wcs[k * NCLS + lane + 32];
    }
    float m = fmaxf(l0, l1);
    if (lane < 8) m = fmaxf(m, l2);
    for (int o = 1; o < 16; o <<= 1) m = fmaxf(m, __shfl_xor(m, o, 64));
    float s = expf(l0 - m) + expf(l1 - m) + ((lane < 8) ? expf(l2 - m) : 0.0f);
    for (int o = 1; o < 16; o <<= 1) s += __shfl_xor(s, o, 64);
    float ls = logf(s) + m;
    out[node * NCLS + lane] = l0 - ls;
    out[node * NCLS + lane + 16] = l1 - ls;
    if (lane < 8) out[node * NCLS + lane + 32] = l2 - ls;
}

extern "C" void kernel_launch(void* const* d_in, const int* in_sizes, int n_in,
                              void* d_out, int out_size, void* d_ws, size_t ws_size,
                              hipStream_t stream) {
    const float* z     = (const float*)d_in[0];
    const int*   eidx  = (const int*)d_in[1];
    const float* eattr = (const float*)d_in[2];
    const float* W1    = (const float*)d_in[3];
    const float* b1    = (const float*)d_in[4];
    const float* W2    = (const float*)d_in[5];
    const float* b2    = (const float*)d_in[6];
    const float* Wc    = (const float*)d_in[7];
    const float* bc    = (const float*)d_in[8];
    float* out = (float*)d_out;

    char* ws = (char*)d_ws;
    const int* rowp = eidx;
    const int* colp = eidx + N_EDGES;

    int nblk = (N_NODES + 255) / 256;               // 391
    int eblk = N_EDGES / 256;                       // 25000
    int sblk = (N_NODES + 1023) / 1024;             // 98
    int gblk = (N_NODES + 63) / 64;                 // 1563
    int ablk = N_NODES / 16;                        // 6250
    int fblk = (N_NODES * HID) / 256;               // 6250
    int exblk = (N_EDGES * HID) / 256;              // 400000

    if (ws_size >= (size_t)WS_T1_NEED) {
        // ---------- tier-1: atomic-free CSR build + fp16 gather tables ----------
        int*    cbase  = (int*)(ws + OFF_CB);
        int*    tot    = (int*)(ws + OFF_TOT);
        float*  dinv   = (float*)(ws + OFF_DINV);
        int*    offs   = (int*)(ws + OFF_OFFS);
        int*    histc  = (int*)(ws + OFF_HIST);     // overlays edata (time-disjoint)
        int*    histex = (int*)(ws + OFF_HISTEX);
        int2*   ebuf1  = (int2*)(ws + OFF_EBUF1);
        int2*   edat   = (int2*)(ws + OFF_EDATA);
        __half* h1     = (__half*)(ws + OFF_H1);
        __half* hb     = (__half*)(ws + OFF_HB);

        k_hist<<<B_PART, 1024, 0, stream>>>(colp, histc);
        k_colscan<<<K_BKT, 1024, 0, stream>>>(histc, histex, tot);
        k_basescan<<<1, 1024, 0, stream>>>(tot, cbase);
        k_partition<<<B_PART, 1024, 0, stream>>>(rowp, colp, eattr, histc, histex, cbase, ebuf1);
        k_bucketsort<<<K_BKT, 1024, 0, stream>>>(ebuf1, cbase, edat, offs, dinv);
        k_gemm1<<<gblk, 256, 0, stream>>>(z, W1, h1, dinv);      // h1 overlays dead ebuf1
        k_agg1<<<ablk, 256, 0, stream>>>(h1, dinv, offs, edat, b1, W2, hb);
        k_agg2<<<ablk, 256, 0, stream>>>(hb, dinv, offs, edat, b2, Wc, bc, out);
    } else if (ws_size >= (size_t)WS_T2_NEED) {
        // ---------- tier-2: atomic-CSR path (R5) ----------
        float*  dinv = (float*)(ws + T2_DINV);
        int*    cnt  = (int*)(ws + T2_CNT);
        int*    offs = (int*)(ws + T2_OFFS);
        int2*   edat = (int2*)(ws + T2_EDATA);
        __half* h1   = (__half*)(ws + T2_H1);
        __half* hb   = (__half*)(ws + T2_HB);
        int*    bsum = (int*)(ws + T2_BSUM);

        k_init<<<nblk, 256, 0, stream>>>(cnt);
        k_count<<<eblk, 256, 0, stream>>>(colp, cnt);
        k_scan1<<<sblk, 1024, 0, stream>>>(cnt, offs, bsum);
        k_scan2<<<1, 128, 0, stream>>>(bsum);
        k_scan3<<<sblk, 1024, 0, stream>>>(offs, cnt, bsum);
        k_scatter<<<eblk, 256, 0, stream>>>(rowp, colp, eattr, cnt, edat);
        k_deg_dinv<<<ablk, 256, 0, stream>>>(offs, edat, dinv);
        k_gemm1<<<gblk, 256, 0, stream>>>(z, W1, h1, dinv);
        k_agg1<<<ablk, 256, 0, stream>>>(h1, dinv, offs, edat, b1, W2, hb);
        k_agg2<<<ablk, 256, 0, stream>>>(hb, dinv, offs, edat, b2, Wc, bc, out);
    } else {
        // ---------- tier-3: edge-atomic fallback (f32 throughout) ----------
        float* deg = (float*)(ws + OFF3_DEG);
        float* h1  = (float*)(ws + OFF3_H1);
        float* hb  = (float*)(ws + OFF3_HB);

        k_init_deg<<<nblk, 256, 0, stream>>>(deg);
        k_deg_only<<<eblk, 256, 0, stream>>>(colp, eattr, deg);
        k_dinv<<<nblk, 256, 0, stream>>>(deg);
        k_gemm1f<<<gblk, 256, 0, stream>>>(z, W1, hb, nullptr);
        k_self<<<fblk, 256, 0, stream>>>(deg, hb, h1);
        k_edge_atomic<<<exblk, 256, 0, stream>>>(rowp, colp, eattr, deg, hb, h1);
        k_bias_relu_gemm2<<<ablk, 256, 0, stream>>>(h1, b1, W2, hb);
        k_self<<<fblk, 256, 0, stream>>>(deg, hb, h1);
        k_edge_atomic<<<exblk, 256, 0, stream>>>(rowp, colp, eattr, deg, hb, h1);
        k_final<<<ablk, 256, 0, stream>>>(h1, b2, Wc, bc, out);
    }
}

// Round 8
// 394.566 us; speedup vs baseline: 4.7094x; 1.0160x over previous
//
#include <hip/hip_runtime.h>
#include <hip/hip_bf16.h>
#include <hip/hip_fp16.h>

// GCN inference: conv1(128->16)+ReLU -> conv2(16->16) -> linear(16->40) -> log_softmax
// R15 post-mortem: LDS-staged bucketsort worked (404->401); both agg kernels now
// top (68us each, HBM 15%, VALU 33%, Occ 70% -- issue/latency-bound gather loop).
// R16: agg restructure 16 lanes/node -> 4 lanes/node with uint2 gathers (4 fp16
// features per lane, same 32B/edge traffic, 1/4 the VMEM instructions and
// addressing; 16 nodes/wave). Finish GEMMs go through padded LDS x[64][17]
// (stride-17 kills bank conflicts); softmax reduces over the 4-lane quad.
// 8-deep unroll retained (16 loads in flight/lane). Build pipeline untouched.

#define N_NODES 100000
#define N_EDGES 6400000
#define IN_DIM  128
#define HID     16
#define NCLS    40

#define K_BKT    782         // buckets = col>>7, 128 nodes each (last: 32)
#define BKT_SH   7
#define BKT_NB   128         // nodes per bucket
#define BKT_MASK 127
#define B_PART   1000        // histogram/partition blocks
#define CHUNK    6400        // edges per partition block (fits LDS staging)
#define BS_CAP   9216        // bucketsort LDS staging capacity (edges)

// ---- tier-1 workspace layout (bytes) ----
#define OFF_CB    0          // int[783] bucket bases
#define OFF_TOT   4096       // int[782] bucket totals
#define OFF_DINV  8192       // float[N]
#define OFF_OFFS  408192     // int[N+1]
#define OFF_EBUF1 808256     // int2[E] bucket-major edges (dead after bucketsort)
#define OFF_EDATA 52008256   // int2[E] final CSR (row, w) -- ends 103,208,256
#define OFF_HIST   OFF_EDATA               // int[1000*782] (dead before bucketsort)
#define OFF_HISTEX (OFF_EDATA + 3128000)   // int[1000*782]
#define WS_T1_NEED 103600000
// h1/hb (fp16, 3.2MB each) overlay the dead ebuf1 region:
#define OFF_H1    OFF_EBUF1
#define OFF_HB    (OFF_EBUF1 + 3200000)

// ---- tier-2 workspace layout (R5 atomic-CSR path, fp16 h) ----
#define T2_DINV  0
#define T2_CNT   400128
#define T2_OFFS  800256
#define T2_EDATA 1200384
#define T2_H1    52400384
#define T2_HB    58800384
#define T2_BSUM  65200384
#define WS_T2_NEED 65210000

// ---- tier-3 fallback layout ----
#define OFF3_DEG 0
#define OFF3_H1  400128
#define OFF3_HB  6800384

// =================== tier-1: deterministic CSR build ===================

__global__ __launch_bounds__(1024) void k_hist(const int* col, int* histcnt) {
    __shared__ int h[K_BKT];
    int t = threadIdx.x;
    if (t < K_BKT) h[t] = 0;
    __syncthreads();
    int b = blockIdx.x;
    const int4* c4 = (const int4*)(col + b * CHUNK);
    for (int i = t; i < CHUNK / 4; i += 1024) {
        int4 c = c4[i];
        atomicAdd(&h[c.x >> BKT_SH], 1);              // LDS int atomic: fast path
        atomicAdd(&h[c.y >> BKT_SH], 1);
        atomicAdd(&h[c.z >> BKT_SH], 1);
        atomicAdd(&h[c.w >> BKT_SH], 1);
    }
    __syncthreads();
    if (t < K_BKT) histcnt[b * K_BKT + t] = h[t];
}

// one block per bucket k: exclusive-scan histcnt[.][k] over the 1000 blocks
__global__ __launch_bounds__(1024) void k_colscan(const int* histcnt, int* histex, int* tot) {
    __shared__ int s[1024];
    int t = threadIdx.x;
    int k = blockIdx.x;
    int v = (t < B_PART) ? histcnt[t * K_BKT + k] : 0;
    s[t] = v;
    __syncthreads();
    for (int o = 1; o < 1024; o <<= 1) {
        int a = (t >= o) ? s[t - o] : 0;
        __syncthreads();
        s[t] += a;
        __syncthreads();
    }
    if (t < B_PART) histex[t * K_BKT + k] = s[t] - v;  // exclusive
    if (t == 0) tot[k] = s[B_PART - 1];                // inclusive total
}

__global__ __launch_bounds__(1024) void k_basescan(const int* tot, int* cbase) {
    __shared__ int s[1024];
    int t = threadIdx.x;
    int v = (t < K_BKT) ? tot[t] : 0;
    s[t] = v;
    __syncthreads();
    for (int o = 1; o < 1024; o <<= 1) {
        int a = (t >= o) ? s[t - o] : 0;
        __syncthreads();
        s[t] += a;
        __syncthreads();
    }
    if (t < K_BKT) cbase[t] = s[t] - v;               // exclusive
    if (t == 0) cbase[K_BKT] = N_EDGES;
}

// LDS-staged partition: counting-sort the block's chunk in LDS, then write
// bucket-segments to global in slot order (coalesced runs).
// packed = row | (col_local<<17)
__global__ __launch_bounds__(1024) void k_partition(const int* row, const int* col,
                                                    const float* w, const int* histcnt,
                                                    const int* histex, const int* cbase,
                                                    int2* ebuf1) {
    __shared__ int2 led[CHUNK];          // 51.2KB staged edges
    __shared__ int  sscan[1024];
    __shared__ int  lbase[K_BKT + 1];
    __shared__ int  gofs[K_BKT];
    __shared__ int  cur[K_BKT];
    int t = threadIdx.x;
    int b = blockIdx.x;
    int v = (t < K_BKT) ? histcnt[b * K_BKT + t] : 0;
    sscan[t] = v;
    __syncthreads();
    for (int o = 1; o < 1024; o <<= 1) {
        int a = (t >= o) ? sscan[t - o] : 0;
        __syncthreads();
        sscan[t] += a;
        __syncthreads();
    }
    if (t < K_BKT) {
        int ex = sscan[t] - v;
        lbase[t] = ex;
        cur[t] = ex;
        gofs[t] = cbase[t] + histex[b * K_BKT + t] - ex;
    }
    if (t == 0) lbase[K_BKT] = CHUNK;
    __syncthreads();
    int end = (b + 1) * CHUNK;
    int e = b * CHUNK + t;
    for (; e + 1024 < end; e += 2048) {
        int c0 = col[e],  c1 = col[e + 1024];
        int r0 = row[e],  r1 = row[e + 1024];
        float w0 = w[e],  w1 = w[e + 1024];
        int p0 = atomicAdd(&cur[c0 >> BKT_SH], 1);
        int p1 = atomicAdd(&cur[c1 >> BKT_SH], 1);
        led[p0] = make_int2(r0 | ((c0 & BKT_MASK) << 17), __float_as_int(w0));
        led[p1] = make_int2(r1 | ((c1 & BKT_MASK) << 17), __float_as_int(w1));
    }
    for (; e < end; e += 1024) {
        int c = col[e];
        int p = atomicAdd(&cur[c >> BKT_SH], 1);
        led[p] = make_int2(row[e] | ((c & BKT_MASK) << 17), __float_as_int(w[e]));
    }
    __syncthreads();
    for (int i = t; i < CHUNK; i += 1024) {
        int2 ed = led[i];
        int lo = 0, hi = K_BKT;
        while (hi - lo > 1) {
            int mid = (lo + hi) >> 1;
            if (lbase[mid] <= i) lo = mid; else hi = mid;
        }
        ebuf1[gofs[lo] + i] = ed;
    }
}

// per-bucket fine counting sort -> edata CSR; also offs + dinv. LDS-staged pass B.
__global__ __launch_bounds__(1024) void k_bucketsort(const int2* ebuf1, const int* cbase,
                                                     int2* edata, int* offs, float* dinv) {
    __shared__ int2  led[BS_CAP];        // 73.7KB sorted staging
    __shared__ int   cnt[BKT_NB];
    __shared__ float degw[BKT_NB];
    __shared__ int   sc[BKT_NB];
    __shared__ int   cur[BKT_NB];
    int t = threadIdx.x;
    int k = blockIdx.x;
    if (t < BKT_NB) { cnt[t] = 0; degw[t] = 0.0f; }
    __syncthreads();
    int e0 = cbase[k], e1 = cbase[k + 1];
    int e = e0 + t;
    for (; e + 3072 < e1; e += 4096) {
        int2 v0 = ebuf1[e];
        int2 v1 = ebuf1[e + 1024];
        int2 v2 = ebuf1[e + 2048];
        int2 v3 = ebuf1[e + 3072];
        int a0 = v0.x >> 17, a1 = v1.x >> 17, a2 = v2.x >> 17, a3 = v3.x >> 17;
        atomicAdd(&cnt[a0], 1); atomicAdd(&degw[a0], __int_as_float(v0.y));
        atomicAdd(&cnt[a1], 1); atomicAdd(&degw[a1], __int_as_float(v1.y));
        atomicAdd(&cnt[a2], 1); atomicAdd(&degw[a2], __int_as_float(v2.y));
        atomicAdd(&cnt[a3], 1); atomicAdd(&degw[a3], __int_as_float(v3.y));
    }
    for (; e < e1; e += 1024) {
        int2 v = ebuf1[e];
        int cl = v.x >> 17;
        atomicAdd(&cnt[cl], 1);
        atomicAdd(&degw[cl], __int_as_float(v.y));
    }
    __syncthreads();
    int c0 = (t < BKT_NB) ? cnt[t] : 0;
    if (t < BKT_NB) sc[t] = c0;
    __syncthreads();
    for (int o = 1; o < BKT_NB; o <<= 1) {
        int a = (t < BKT_NB && t >= o) ? sc[t - o] : 0;
        __syncthreads();
        if (t < BKT_NB) sc[t] += a;
        __syncthreads();
    }
    if (t < BKT_NB) {
        int ex = sc[t] - c0;
        cur[t] = ex;                                  // local position base
        int node = k * BKT_NB + t;
        if (node < N_NODES) {
            offs[node] = e0 + ex;
            dinv[node] = rsqrtf(1.0f + degw[t]);
        }
    }
    if (k == 0 && t == 0) offs[N_NODES] = N_EDGES;
    __syncthreads();
    int len = e1 - e0;
    if (len <= BS_CAP) {
        e = e0 + t;
        for (; e + 3072 < e1; e += 4096) {
            int2 v0 = ebuf1[e];
            int2 v1 = ebuf1[e + 1024];
            int2 v2 = ebuf1[e + 2048];
            int2 v3 = ebuf1[e + 3072];
            int p0 = atomicAdd(&cur[v0.x >> 17], 1);
            int p1 = atomicAdd(&cur[v1.x >> 17], 1);
            int p2 = atomicAdd(&cur[v2.x >> 17], 1);
            int p3 = atomicAdd(&cur[v3.x >> 17], 1);
            led[p0] = make_int2(v0.x & 131071, v0.y);
            led[p1] = make_int2(v1.x & 131071, v1.y);
            led[p2] = make_int2(v2.x & 131071, v2.y);
            led[p3] = make_int2(v3.x & 131071, v3.y);
        }
        for (; e < e1; e += 1024) {
            int2 v = ebuf1[e];
            int p = atomicAdd(&cur[v.x >> 17], 1);
            led[p] = make_int2(v.x & 131071, v.y);
        }
        __syncthreads();
        for (int i = t; i < len; i += 1024)
            edata[e0 + i] = led[i];
    } else {
        e = e0 + t;
        for (; e < e1; e += 1024) {
            int2 v = ebuf1[e];
            int p = atomicAdd(&cur[v.x >> 17], 1);
            edata[e0 + p] = make_int2(v.x & 131071, v.y);
        }
    }
}

// =================== shared compute kernels ===================

// h1 = fp16(dinv[node] * (z @ W1))
__global__ __launch_bounds__(256) void k_gemm1(const float* z, const float* W1,
                                               __half* h1, const float* dinv) {
    __shared__ float w1s[IN_DIM * HID];
    __shared__ float zs[64 * 132];
    int tid = threadIdx.x;
    for (int i = tid; i < IN_DIM * HID / 4; i += 256)
        ((float4*)w1s)[i] = ((const float4*)W1)[i];
    int nodeBase = blockIdx.x * 64;
    for (int i = tid; i < 64 * 32; i += 256) {
        int nl = i >> 5, kq = i & 31;
        int node = nodeBase + nl;
        float4 v = (node < N_NODES) ? ((const float4*)z)[node * 32 + kq]
                                    : make_float4(0.f, 0.f, 0.f, 0.f);
        *(float4*)&zs[nl * 132 + kq * 4] = v;
    }
    __syncthreads();
    int nl = tid >> 2;
    int jb = (tid & 3) * 4;
    int node = nodeBase + nl;
    float4 acc = make_float4(0.f, 0.f, 0.f, 0.f);
    for (int k = 0; k < IN_DIM; k++) {
        float s = zs[nl * 132 + k];
        float4 wv = *(const float4*)&w1s[k * HID + jb];
        acc.x += s * wv.x; acc.y += s * wv.y; acc.z += s * wv.z; acc.w += s * wv.w;
    }
    if (node < N_NODES) {
        float dv = dinv ? dinv[node] : 1.0f;
        union { __half2 h2[2]; uint2 u; } pk;
        pk.h2[0] = __floats2half2_rn(acc.x * dv, acc.y * dv);
        pk.h2[1] = __floats2half2_rn(acc.z * dv, acc.w * dv);
        ((uint2*)h1)[node * 4 + (tid & 3)] = pk.u;
    }
}

// f32-output variant for tier-3
__global__ __launch_bounds__(256) void k_gemm1f(const float* z, const float* W1, float* h1,
                                                const float* dinv) {
    __shared__ float w1s[IN_DIM * HID];
    __shared__ float zs[64 * 132];
    int tid = threadIdx.x;
    for (int i = tid; i < IN_DIM * HID / 4; i += 256)
        ((float4*)w1s)[i] = ((const float4*)W1)[i];
    int nodeBase = blockIdx.x * 64;
    for (int i = tid; i < 64 * 32; i += 256) {
        int nl = i >> 5, kq = i & 31;
        int node = nodeBase + nl;
        float4 v = (node < N_NODES) ? ((const float4*)z)[node * 32 + kq]
                                    : make_float4(0.f, 0.f, 0.f, 0.f);
        *(float4*)&zs[nl * 132 + kq * 4] = v;
    }
    __syncthreads();
    int nl = tid >> 2;
    int jb = (tid & 3) * 4;
    int node = nodeBase + nl;
    float4 acc = make_float4(0.f, 0.f, 0.f, 0.f);
    for (int k = 0; k < IN_DIM; k++) {
        float s = zs[nl * 132 + k];
        float4 wv = *(const float4*)&w1s[k * HID + jb];
        acc.x += s * wv.x; acc.y += s * wv.y; acc.z += s * wv.z; acc.w += s * wv.w;
    }
    if (node < N_NODES) {
        float dv = dinv ? dinv[node] : 1.0f;
        acc.x *= dv; acc.y *= dv; acc.z *= dv; acc.w *= dv;
        ((float4*)h1)[node * 4 + (tid & 3)] = acc;
    }
}

// 4-lane/node edge aggregation: each lane gathers uint2 = 4 fp16 features.
// 8-deep unroll -> 16 loads in flight per lane; 16 nodes per wave.
__device__ __forceinline__ void edge_agg4(const __half* __restrict__ h,
                                          const int2* __restrict__ edata,
                                          int e0, int e1, int lane, float4& acc) {
    const uint2* hq = (const uint2*)h;
    int e = e0;
    for (; e + 8 <= e1; e += 8) {
        int2 d0 = edata[e];
        int2 d1 = edata[e + 1];
        int2 d2 = edata[e + 2];
        int2 d3 = edata[e + 3];
        int2 d4 = edata[e + 4];
        int2 d5 = edata[e + 5];
        int2 d6 = edata[e + 6];
        int2 d7 = edata[e + 7];
        uint2 g0 = hq[d0.x * 4 + lane];
        uint2 g1 = hq[d1.x * 4 + lane];
        uint2 g2 = hq[d2.x * 4 + lane];
        uint2 g3 = hq[d3.x * 4 + lane];
        uint2 g4 = hq[d4.x * 4 + lane];
        uint2 g5 = hq[d5.x * 4 + lane];
        uint2 g6 = hq[d6.x * 4 + lane];
        uint2 g7 = hq[d7.x * 4 + lane];
        #define ACC4(d, g) { \
            float wv = __int_as_float((d).y); \
            __half2 a = *(__half2*)&(g).x; \
            __half2 b = *(__half2*)&(g).y; \
            float2 fa = __half22float2(a); \
            float2 fb = __half22float2(b); \
            acc.x += wv * fa.x; acc.y += wv * fa.y; \
            acc.z += wv * fb.x; acc.w += wv * fb.y; }
        ACC4(d0, g0) ACC4(d1, g1) ACC4(d2, g2) ACC4(d3, g3)
        ACC4(d4, g4) ACC4(d5, g5) ACC4(d6, g6) ACC4(d7, g7)
    }
    for (; e < e1; e++) {
        int2 d = edata[e];
        uint2 g = hq[d.x * 4 + lane];
        ACC4(d, g)
        #undef ACC4
    }
}

// conv1 aggregate (+b1, ReLU), fused h2 = x1 @ W2; hb = fp16(dinv * h2)
// 256 threads = 64 nodes (4 lanes each); finish via padded LDS x1s[64][17].
__global__ __launch_bounds__(256) void k_agg1(const __half* __restrict__ h1,
                                              const float* __restrict__ dinv,
                                              const int* __restrict__ offs,
                                              const int2* __restrict__ edata,
                                              const float* __restrict__ b1,
                                              const float* __restrict__ W2,
                                              __half* __restrict__ hb) {
    __shared__ float w2s[HID * HID];
    __shared__ float x1s[64 * 17];       // +1 pad: conflict-free column reads
    int tid = threadIdx.x;
    if (tid < HID * HID) w2s[tid] = W2[tid];
    int lane = tid & 3;
    int g = tid >> 2;
    int node = blockIdx.x * 64 + g;
    bool valid = node < N_NODES;
    int e0 = valid ? offs[node] : 0;
    int e1 = valid ? offs[node + 1] : 0;
    float4 acc = make_float4(0.f, 0.f, 0.f, 0.f);
    float d = 0.0f;
    if (valid) {
        uint2 sv = ((const uint2*)h1)[node * 4 + lane];
        __half2 s0 = *(__half2*)&sv.x;
        __half2 s1 = *(__half2*)&sv.y;
        float2 f0 = __half22float2(s0);
        float2 f1 = __half22float2(s1);
        acc = make_float4(f0.x, f0.y, f1.x, f1.y);
        d = dinv[node];
    }
    edge_agg4(h1, edata, e0, e1, lane, acc);
    if (valid) {
        float4 bb = *(const float4*)&b1[lane * 4];
        acc.x = fmaxf(d * acc.x + bb.x, 0.0f);
        acc.y = fmaxf(d * acc.y + bb.y, 0.0f);
        acc.z = fmaxf(d * acc.z + bb.z, 0.0f);
        acc.w = fmaxf(d * acc.w + bb.w, 0.0f);
        *(float4*)&x1s[g * 17 + lane * 4] = acc;
    }
    __syncthreads();
    if (valid) {
        float4 h2 = make_float4(0.f, 0.f, 0.f, 0.f);
        #pragma unroll
        for (int kk = 0; kk < HID; kk++) {
            float v = x1s[g * 17 + kk];
            float4 wv = *(const float4*)&w2s[kk * HID + lane * 4];
            h2.x += v * wv.x; h2.y += v * wv.y; h2.z += v * wv.z; h2.w += v * wv.w;
        }
        union { __half2 p[2]; uint2 u; } pk;
        pk.p[0] = __floats2half2_rn(d * h2.x, d * h2.y);
        pk.p[1] = __floats2half2_rn(d * h2.z, d * h2.w);
        ((uint2*)hb)[node * 4 + lane] = pk.u;
    }
}

// conv2 aggregate (+b2), classifier (16->40) + log_softmax; 4 lanes/node,
// each lane owns 10 classifier outputs; quad shfl_xor softmax reduce.
__global__ __launch_bounds__(256) void k_agg2(const __half* __restrict__ hb,
                                              const float* __restrict__ dinv,
                                              const int* __restrict__ offs,
                                              const int2* __restrict__ edata,
                                              const float* __restrict__ b2,
                                              const float* __restrict__ Wc,
                                              const float* __restrict__ bc,
                                              float* __restrict__ out) {
    __shared__ float wcs[HID * NCLS];    // 640 floats
    __shared__ float bcs[NCLS];
    __shared__ float x2s[64 * 17];
    int tid = threadIdx.x;
    for (int i = tid; i < HID * NCLS; i += 256) wcs[i] = Wc[i];
    if (tid < NCLS) bcs[tid] = bc[tid];
    int lane = tid & 3;
    int g = tid >> 2;
    int node = blockIdx.x * 64 + g;
    bool valid = node < N_NODES;
    int e0 = valid ? offs[node] : 0;
    int e1 = valid ? offs[node + 1] : 0;
    float4 acc = make_float4(0.f, 0.f, 0.f, 0.f);
    float d = 0.0f;
    if (valid) {
        uint2 sv = ((const uint2*)hb)[node * 4 + lane];
        __half2 s0 = *(__half2*)&sv.x;
        __half2 s1 = *(__half2*)&sv.y;
        float2 f0 = __half22float2(s0);
        float2 f1 = __half22float2(s1);
        acc = make_float4(f0.x, f0.y, f1.x, f1.y);
        d = dinv[node];
    }
    edge_agg4(hb, edata, e0, e1, lane, acc);
    if (valid) {
        float4 bb = *(const float4*)&b2[lane * 4];
        acc.x = d * acc.x + bb.x;
        acc.y = d * acc.y + bb.y;
        acc.z = d * acc.z + bb.z;
        acc.w = d * acc.w + bb.w;
        *(float4*)&x2s[g * 17 + lane * 4] = acc;
    }
    __syncthreads();
    if (valid) {
        float l[10];
        #pragma unroll
        for (int c = 0; c < 10; c++) l[c] = bcs[lane * 10 + c];
        #pragma unroll
        for (int kk = 0; kk < HID; kk++) {
            float v = x2s[g * 17 + kk];
            #pragma unroll
            for (int c = 0; c < 10; c++)
                l[c] += v * wcs[kk * NCLS + lane * 10 + c];
        }
        float m = l[0];
        #pragma unroll
        for (int c = 1; c < 10; c++) m = fmaxf(m, l[c]);
        m = fmaxf(m, __shfl_xor(m, 1, 64));
        m = fmaxf(m, __shfl_xor(m, 2, 64));
        float s = 0.0f;
        #pragma unroll
        for (int c = 0; c < 10; c++) s += expf(l[c] - m);
        s += __shfl_xor(s, 1, 64);
        s += __shfl_xor(s, 2, 64);
        float ls = logf(s) + m;
        #pragma unroll
        for (int c = 0; c < 10; c++)
            out[node * NCLS + lane * 10 + c] = l[c] - ls;
    }
}

// =================== tier-2: R5 atomic-CSR build ===================

__global__ __launch_bounds__(256) void k_init(int* cnt) {
    int i = blockIdx.x * 256 + threadIdx.x;
    if (i < N_NODES) cnt[i] = 0;
}

__global__ __launch_bounds__(256) void k_count(const int* col, int* cnt) {
    int e = blockIdx.x * 256 + threadIdx.x;
    atomicAdd(&cnt[col[e]], 1);
}

__global__ __launch_bounds__(1024) void k_scan1(const int* cnt, int* offs, int* bsum) {
    __shared__ int s[1024];
    int tid = threadIdx.x;
    int gid = blockIdx.x * 1024 + tid;
    int v = (gid < N_NODES) ? cnt[gid] : 0;
    s[tid] = v;
    __syncthreads();
    for (int o = 1; o < 1024; o <<= 1) {
        int t = (tid >= o) ? s[tid - o] : 0;
        __syncthreads();
        s[tid] += t;
        __syncthreads();
    }
    if (gid < N_NODES) offs[gid] = s[tid] - v;
    if (tid == 1023) bsum[blockIdx.x] = s[1023];
}

__global__ __launch_bounds__(128) void k_scan2(int* bsum) {
    __shared__ int s[128];
    int tid = threadIdx.x;
    int v = (tid < 98) ? bsum[tid] : 0;
    s[tid] = v;
    __syncthreads();
    for (int o = 1; o < 128; o <<= 1) {
        int t = (tid >= o) ? s[tid - o] : 0;
        __syncthreads();
        s[tid] += t;
        __syncthreads();
    }
    if (tid < 98) bsum[tid] = s[tid] - v;
}

__global__ __launch_bounds__(1024) void k_scan3(int* offs, int* cur, const int* bsum) {
    int tid = threadIdx.x;
    int gid = blockIdx.x * 1024 + tid;
    if (gid < N_NODES) {
        int o = offs[gid] + bsum[blockIdx.x];
        offs[gid] = o;
        cur[gid] = o;
    }
    if (gid == 0) offs[N_NODES] = N_EDGES;
}

__global__ __launch_bounds__(256) void k_scatter(const int* row, const int* col,
                                                 const float* w, int* cur, int2* edata) {
    int e = blockIdx.x * 256 + threadIdx.x;
    int r = row[e];
    int c = col[e];
    int p = atomicAdd(&cur[c], 1);
    edata[p] = make_int2(r, __float_as_int(w[e]));
}

__global__ __launch_bounds__(256) void k_deg_dinv(const int* offs, const int2* edata,
                                                  float* dinv) {
    int tid = threadIdx.x;
    int lane = tid & 15;
    int node = blockIdx.x * 16 + (tid >> 4);
    int e0 = offs[node], e1 = offs[node + 1];
    float s = 0.0f;
    for (int e = e0 + lane; e < e1; e += 16)
        s += __int_as_float(edata[e].y);
    for (int o = 1; o < 16; o <<= 1) s += __shfl_xor(s, o, 64);
    if (lane == 0) dinv[node] = 1.0f / sqrtf(1.0f + s);
}

// =================== tier-3: edge-atomic fallback ===================

__global__ __launch_bounds__(256) void k_init_deg(float* deg) {
    int i = blockIdx.x * 256 + threadIdx.x;
    if (i < N_NODES) deg[i] = 1.0f;
}

__global__ __launch_bounds__(256) void k_deg_only(const int* col, const float* w, float* deg) {
    int e = blockIdx.x * 256 + threadIdx.x;
    atomicAdd(&deg[col[e]], w[e]);
}

__global__ __launch_bounds__(256) void k_dinv(float* deg) {
    int i = blockIdx.x * 256 + threadIdx.x;
    if (i < N_NODES) {
        float d = deg[i];
        deg[i] = (d > 0.0f) ? 1.0f / sqrtf(d) : 0.0f;
    }
}

__global__ __launch_bounds__(256) void k_self(const float* dinv, const float* h, float* agg) {
    int i = blockIdx.x * 256 + threadIdx.x;
    float d = dinv[i >> 4];
    agg[i] = d * d * h[i];
}

__global__ __launch_bounds__(256) void k_edge_atomic(const int* row, const int* col,
                                                     const float* w, const float* dinv,
                                                     const float* h, float* agg) {
    int gid = blockIdx.x * 256 + threadIdx.x;
    int e = gid >> 4, lane = gid & 15;
    int r = row[e], c = col[e];
    float nrm = dinv[r] * w[e] * dinv[c];
    atomicAdd(&agg[c * HID + lane], nrm * h[r * HID + lane]);
}

__global__ __launch_bounds__(256) void k_bias_relu_gemm2(const float* agg, const float* b1,
                                                         const float* W2, float* out2) {
    __shared__ float w2s[HID * HID];
    int tid = threadIdx.x;
    if (tid < HID * HID) w2s[tid] = W2[tid];
    __syncthreads();
    int lane = tid & 15;
    int node = blockIdx.x * 16 + (tid >> 4);
    float acc = fmaxf(agg[node * HID + lane] + b1[lane], 0.0f);
    int base = tid & 48;
    float h2 = 0.0f;
    for (int k = 0; k < HID; k++) {
        float v = __shfl(acc, base + k, 64);
        h2 += v * w2s[k * HID + lane];
    }
    out2[node * HID + lane] = h2;
}

__global__ __launch_bounds__(256) void k_final(const float* agg, const float* b2,
                                               const float* Wc, const float* bc, float* out) {
    __shared__ float wcs[HID * NCLS];
    __shared__ float bcs[NCLS];
    int tid = threadIdx.x;
    for (int i = tid; i < HID * NCLS; i += 256) wcs[i] = Wc[i];
    if (tid < NCLS) bcs[tid] = bc[tid];
    __syncthreads();
    int lane = tid & 15;
    int node = blockIdx.x * 16 + (tid >> 4);
    float acc = agg[node * HID + lane] + b2[lane];
    float l0 = bcs[lane];
    float l1 = bcs[lane + 16];
    float l2 = (lane < 8) ? bcs[lane + 32] : 0.0f;
    int base = tid & 48;
    for (int k = 0; k < HID; k++) {
        float v = __shfl(acc, base + k, 64);
        l0 += v * wcs[k * NCLS + lane];
        l1 += v * wcs[k * NCLS + lane + 16];
        if (lane < 8) l2 += v * wcs[k * NCLS + lane + 32];
    }
    float m = fmaxf(l0, l1);
    if (lane < 8) m = fmaxf(m, l2);
    for (int o = 1; o < 16; o <<= 1) m = fmaxf(m, __shfl_xor(m, o, 64));
    float s = expf(l0 - m) + expf(l1 - m) + ((lane < 8) ? expf(l2 - m) : 0.0f);
    for (int o = 1; o < 16; o <<= 1) s += __shfl_xor(s, o, 64);
    float ls = logf(s) + m;
    out[node * NCLS + lane] = l0 - ls;
    out[node * NCLS + lane + 16] = l1 - ls;
    if (lane < 8) out[node * NCLS + lane + 32] = l2 - ls;
}

extern "C" void kernel_launch(void* const* d_in, const int* in_sizes, int n_in,
                              void* d_out, int out_size, void* d_ws, size_t ws_size,
                              hipStream_t stream) {
    const float* z     = (const float*)d_in[0];
    const int*   eidx  = (const int*)d_in[1];
    const float* eattr = (const float*)d_in[2];
    const float* W1    = (const float*)d_in[3];
    const float* b1    = (const float*)d_in[4];
    const float* W2    = (const float*)d_in[5];
    const float* b2    = (const float*)d_in[6];
    const float* Wc    = (const float*)d_in[7];
    const float* bc    = (const float*)d_in[8];
    float* out = (float*)d_out;

    char* ws = (char*)d_ws;
    const int* rowp = eidx;
    const int* colp = eidx + N_EDGES;

    int nblk = (N_NODES + 255) / 256;               // 391
    int eblk = N_EDGES / 256;                       // 25000
    int sblk = (N_NODES + 1023) / 1024;             // 98
    int gblk = (N_NODES + 63) / 64;                 // 1563
    int ablk = (N_NODES + 63) / 64;                 // 1563 (4-lane agg: 64 nodes/block)
    int a16  = N_NODES / 16;                        // 6250 (16-lane helpers)
    int fblk = (N_NODES * HID) / 256;               // 6250
    int exblk = (N_EDGES * HID) / 256;              // 400000

    if (ws_size >= (size_t)WS_T1_NEED) {
        // ---------- tier-1: atomic-free CSR build + fp16 gather tables ----------
        int*    cbase  = (int*)(ws + OFF_CB);
        int*    tot    = (int*)(ws + OFF_TOT);
        float*  dinv   = (float*)(ws + OFF_DINV);
        int*    offs   = (int*)(ws + OFF_OFFS);
        int*    histc  = (int*)(ws + OFF_HIST);     // overlays edata (time-disjoint)
        int*    histex = (int*)(ws + OFF_HISTEX);
        int2*   ebuf1  = (int2*)(ws + OFF_EBUF1);
        int2*   edat   = (int2*)(ws + OFF_EDATA);
        __half* h1     = (__half*)(ws + OFF_H1);
        __half* hb     = (__half*)(ws + OFF_HB);

        k_hist<<<B_PART, 1024, 0, stream>>>(colp, histc);
        k_colscan<<<K_BKT, 1024, 0, stream>>>(histc, histex, tot);
        k_basescan<<<1, 1024, 0, stream>>>(tot, cbase);
        k_partition<<<B_PART, 1024, 0, stream>>>(rowp, colp, eattr, histc, histex, cbase, ebuf1);
        k_bucketsort<<<K_BKT, 1024, 0, stream>>>(ebuf1, cbase, edat, offs, dinv);
        k_gemm1<<<gblk, 256, 0, stream>>>(z, W1, h1, dinv);      // h1 overlays dead ebuf1
        k_agg1<<<ablk, 256, 0, stream>>>(h1, dinv, offs, edat, b1, W2, hb);
        k_agg2<<<ablk, 256, 0, stream>>>(hb, dinv, offs, edat, b2, Wc, bc, out);
    } else if (ws_size >= (size_t)WS_T2_NEED) {
        // ---------- tier-2: atomic-CSR path (R5) ----------
        float*  dinv = (float*)(ws + T2_DINV);
        int*    cnt  = (int*)(ws + T2_CNT);
        int*    offs = (int*)(ws + T2_OFFS);
        int2*   edat = (int2*)(ws + T2_EDATA);
        __half* h1   = (__half*)(ws + T2_H1);
        __half* hb   = (__half*)(ws + T2_HB);
        int*    bsum = (int*)(ws + T2_BSUM);

        k_init<<<nblk, 256, 0, stream>>>(cnt);
        k_count<<<eblk, 256, 0, stream>>>(colp, cnt);
        k_scan1<<<sblk, 1024, 0, stream>>>(cnt, offs, bsum);
        k_scan2<<<1, 128, 0, stream>>>(bsum);
        k_scan3<<<sblk, 1024, 0, stream>>>(offs, cnt, bsum);
        k_scatter<<<eblk, 256, 0, stream>>>(rowp, colp, eattr, cnt, edat);
        k_deg_dinv<<<a16, 256, 0, stream>>>(offs, edat, dinv);
        k_gemm1<<<gblk, 256, 0, stream>>>(z, W1, h1, dinv);
        k_agg1<<<ablk, 256, 0, stream>>>(h1, dinv, offs, edat, b1, W2, hb);
        k_agg2<<<ablk, 256, 0, stream>>>(hb, dinv, offs, edat, b2, Wc, bc, out);
    } else {
        // ---------- tier-3: edge-atomic fallback (f32 throughout) ----------
        float* deg = (float*)(ws + OFF3_DEG);
        float* h1  = (float*)(ws + OFF3_H1);
        float* hb  = (float*)(ws + OFF3_HB);

        k_init_deg<<<nblk, 256, 0, stream>>>(deg);
        k_deg_only<<<eblk, 256, 0, stream>>>(colp, eattr, deg);
        k_dinv<<<nblk, 256, 0, stream>>>(deg);
        k_gemm1f<<<gblk, 256, 0, stream>>>(z, W1, hb, nullptr);
        k_self<<<fblk, 256, 0, stream>>>(deg, hb, h1);
        k_edge_atomic<<<exblk, 256, 0, stream>>>(rowp, colp, eattr, deg, hb, h1);
        k_bias_relu_gemm2<<<a16, 256, 0, stream>>>(h1, b1, W2, hb);
        k_self<<<fblk, 256, 0, stream>>>(deg, hb, h1);
        k_edge_atomic<<<exblk, 256, 0, stream>>>(rowp, colp, eattr, deg, hb, h1);
        k_final<<<a16, 256, 0, stream>>>(h1, b2, Wc, bc, out);
    }
}